// Round 1
// baseline (201.879 us; speedup 1.0000x reference)
//
#include <hip/hip_runtime.h>
#include <hip/hip_bf16.h>

typedef unsigned short u16;
typedef short bf16x8 __attribute__((ext_vector_type(8)));
typedef u16 u16x8 __attribute__((ext_vector_type(8)));
typedef float f32x4 __attribute__((ext_vector_type(4)));

#define D_MODEL 512
#define L_SEQ 2048
#define B_SZ 4
#define N_HEADS 8
#define D_K 64
#define M_ROWS (B_SZ * L_SEQ)   /* 8192 */
#define NQKV (3 * D_MODEL)      /* 1536 */
#define WIN 10
#define KDIM 512

__device__ inline u16 f2bf(float x) {
  __hip_bfloat16 h = __float2bfloat16(x);
  return *reinterpret_cast<u16*>(&h);
}
__device__ inline float bf2f(u16 u) {
  __hip_bfloat16 h;
  *reinterpret_cast<u16*>(&h) = u;
  return __bfloat162float(h);
}

// ---------------- pack X -> hi/lo bf16 ----------------
__global__ void pack_x(const float* __restrict__ X, u16* __restrict__ Xh,
                       u16* __restrict__ Xl, int n) {
  int i = blockIdx.x * blockDim.x + threadIdx.x;
  if (i >= n) return;
  float x = X[i];
  u16 hi = f2bf(x);
  u16 lo = f2bf(x - bf2f(hi));
  Xh[i] = hi;
  Xl[i] = lo;
}

// ---------------- pack weights transposed -> [N][K] hi/lo bf16 ----------------
__global__ void pack_w(const float* __restrict__ Wq, const float* __restrict__ Wk,
                       const float* __restrict__ Wv, const float* __restrict__ Wo,
                       u16* __restrict__ Bqkv_h, u16* __restrict__ Bqkv_l,
                       u16* __restrict__ Bo_h, u16* __restrict__ Bo_l) {
  int i = blockIdx.x * blockDim.x + threadIdx.x;  // 4*512*512
  int which = i >> 18;
  int r = i & 262143;
  int n = r >> 9;   // output col of W
  int k = r & 511;  // input dim
  const float* W = which == 0 ? Wq : which == 1 ? Wk : which == 2 ? Wv : Wo;
  float x = W[k * 512 + n];
  u16 hi = f2bf(x);
  u16 lo = f2bf(x - bf2f(hi));
  if (which < 3) {
    size_t o = ((size_t)(which * 512 + n)) * 512 + k;
    Bqkv_h[o] = hi; Bqkv_l[o] = lo;
  } else {
    size_t o = (size_t)n * 512 + k;
    Bo_h[o] = hi; Bo_l[o] = lo;
  }
}

__global__ void pack_bias(const float* __restrict__ bq, const float* __restrict__ bk,
                          const float* __restrict__ bv, float* __restrict__ bqkv) {
  int i = blockIdx.x * blockDim.x + threadIdx.x;
  if (i < 512) bqkv[i] = bq[i];
  else if (i < 1024) bqkv[i] = bk[i - 512];
  else if (i < 1536) bqkv[i] = bv[i - 1024];
}

// ---------------- split-bf16 GEMM: C[M][N] = A[M][K] * B[N][K]^T + bias ----------------
// A given as hi/lo bf16 row-major [M][K]; B as hi/lo bf16 row-major [N][K] (pre-transposed).
// 3-product split: Ah*Bh + Ah*Bl + Al*Bh  (fp32-quality).
#define BM 128
#define BN 128
#define BK 32
#define LDK 40  /* +8 bf16 pad -> 80B row stride, ~2-way LDS banking */

__global__ __launch_bounds__(256) void gemm_split(
    const u16* __restrict__ Ah, const u16* __restrict__ Al,
    const u16* __restrict__ Bh, const u16* __restrict__ Bl,
    const float* __restrict__ bias, float* __restrict__ C, int N) {
  __shared__ u16 sAh[BM * LDK], sAl[BM * LDK], sBh[BN * LDK], sBl[BN * LDK];
  int t = threadIdx.x;
  int m0 = blockIdx.y * BM;
  int n0 = blockIdx.x * BN;
  int w = t >> 6, lane = t & 63;
  int wm = (w >> 1) * 64, wn = (w & 1) * 64;
  int fr = lane & 15, fo = (lane >> 4) * 8;

  f32x4 acc[4][4] = {};

  for (int kt = 0; kt < KDIM; kt += BK) {
    __syncthreads();
    // stage 128x32 of each of the 4 arrays; 512 16B-chunks each, 2 per thread
#pragma unroll
    for (int it = 0; it < 2; ++it) {
      int c = t + it * 256;
      int row = c >> 2;
      int col = (c & 3) << 3;
      size_t ga = (size_t)(m0 + row) * KDIM + kt + col;
      size_t gb = (size_t)(n0 + row) * KDIM + kt + col;
      *(u16x8*)&sAh[row * LDK + col] = *(const u16x8*)(Ah + ga);
      *(u16x8*)&sAl[row * LDK + col] = *(const u16x8*)(Al + ga);
      *(u16x8*)&sBh[row * LDK + col] = *(const u16x8*)(Bh + gb);
      *(u16x8*)&sBl[row * LDK + col] = *(const u16x8*)(Bl + gb);
    }
    __syncthreads();

    bf16x8 ah[4], al[4], bh[4], bl[4];
#pragma unroll
    for (int m = 0; m < 4; ++m) {
      int ar = wm + m * 16 + fr;
      ah[m] = *(const bf16x8*)&sAh[ar * LDK + fo];
      al[m] = *(const bf16x8*)&sAl[ar * LDK + fo];
      int br = wn + m * 16 + fr;
      bh[m] = *(const bf16x8*)&sBh[br * LDK + fo];
      bl[m] = *(const bf16x8*)&sBl[br * LDK + fo];
    }
#pragma unroll
    for (int m = 0; m < 4; ++m)
#pragma unroll
      for (int n = 0; n < 4; ++n) {
        acc[m][n] = __builtin_amdgcn_mfma_f32_16x16x32_bf16(ah[m], bh[n], acc[m][n], 0, 0, 0);
        acc[m][n] = __builtin_amdgcn_mfma_f32_16x16x32_bf16(ah[m], bl[n], acc[m][n], 0, 0, 0);
        acc[m][n] = __builtin_amdgcn_mfma_f32_16x16x32_bf16(al[m], bh[n], acc[m][n], 0, 0, 0);
      }
  }

  // epilogue: D frag mapping col = lane&15, row = 4*(lane>>4) + reg
  int rbase = m0 + wm + ((lane >> 4) << 2);
  int cbase = n0 + wn + fr;
#pragma unroll
  for (int n = 0; n < 4; ++n) {
    int cc = cbase + n * 16;
    float bn = bias[cc];
#pragma unroll
    for (int m = 0; m < 4; ++m) {
      int rr = rbase + m * 16;
#pragma unroll
      for (int q = 0; q < 4; ++q)
        C[(size_t)(rr + q) * N + cc] = acc[m][n][q] + bn;
    }
  }
}

// ---------------- windowed attention, fp32, one wave per (b,h,row) ----------------
// QKV layout: [8192][1536] fp32, cols 0..511=q, 512..1023=k, 1024..1535=v, col=h*64+d.
// Output written as hi/lo bf16 [8192][512] (concat heads) for the O projection.
__global__ __launch_bounds__(256) void attn_win(const float* __restrict__ QKV,
                                                u16* __restrict__ AOh,
                                                u16* __restrict__ AOl) {
  int gw = (blockIdx.x * 256 + threadIdx.x) >> 6;  // wave id in [0, 65536)
  int lane = threadIdx.x & 63;
  int l = gw & (L_SEQ - 1);
  int bh = gw >> 11;
  int h = bh & (N_HEADS - 1);
  int b = bh >> 3;
  int r = (b << 11) | l;  // memory row

  const float* base = QKV + (size_t)(b << 11) * NQKV + h * D_K + lane;
  float qd = base[(size_t)l * NQKV];
  const float* Kp = base + 512;
  const float* Vp = base + 1024;

  int jlo = l - WIN; if (jlo < 0) jlo = 0;
  int jhi = l + WIN; if (jhi > L_SEQ - 1) jhi = L_SEQ - 1;

  float m = -3.0e38f, lsum = 0.f, acc = 0.f;
  for (int j = jlo; j <= jhi; ++j) {
    float kd = Kp[(size_t)j * NQKV];
    float vd = Vp[(size_t)j * NQKV];
    float p = qd * kd;
#pragma unroll
    for (int off = 32; off; off >>= 1) p += __shfl_xor(p, off);
    float s = p * 0.125f;  // D_K^-0.5
    s = fminf(fmaxf(s, -10000.f), 10000.f);
    float mn = fmaxf(m, s);
    float sc = __expf(m - mn);
    float e = __expf(s - mn);
    lsum = lsum * sc + e;
    acc = acc * sc + e * vd;
    m = mn;
  }
  float o = acc / lsum;
  u16 hi = f2bf(o);
  u16 lo = f2bf(o - bf2f(hi));
  size_t oo = (size_t)r * D_MODEL + h * D_K + lane;
  AOh[oo] = hi;
  AOl[oo] = lo;
}

extern "C" void kernel_launch(void* const* d_in, const int* in_sizes, int n_in,
                              void* d_out, int out_size, void* d_ws, size_t ws_size,
                              hipStream_t stream) {
  const float* Q  = (const float*)d_in[0];
  const float* Wq = (const float*)d_in[1];
  const float* bq = (const float*)d_in[2];
  const float* Wk = (const float*)d_in[3];
  const float* bk = (const float*)d_in[4];
  const float* Wv = (const float*)d_in[5];
  const float* bv = (const float*)d_in[6];
  const float* Wo = (const float*)d_in[7];
  const float* bo = (const float*)d_in[8];
  float* out = (float*)d_out;

  char* p = (char*)d_ws;
  u16* Xh = (u16*)p;       p += (size_t)M_ROWS * 512 * 2;
  u16* Xl = (u16*)p;       p += (size_t)M_ROWS * 512 * 2;
  u16* Bqkv_h = (u16*)p;   p += (size_t)1536 * 512 * 2;
  u16* Bqkv_l = (u16*)p;   p += (size_t)1536 * 512 * 2;
  u16* Bo_h = (u16*)p;     p += (size_t)512 * 512 * 2;
  u16* Bo_l = (u16*)p;     p += (size_t)512 * 512 * 2;
  float* bias_qkv = (float*)p; p += 1536 * 4;
  float* QKV = (float*)p;  p += (size_t)M_ROWS * 1536 * 4;
  u16* AOh = (u16*)p;      p += (size_t)M_ROWS * 512 * 2;
  u16* AOl = (u16*)p;      p += (size_t)M_ROWS * 512 * 2;

  hipLaunchKernelGGL(pack_x, dim3((M_ROWS * 512) / 256), dim3(256), 0, stream,
                     Q, Xh, Xl, M_ROWS * 512);
  hipLaunchKernelGGL(pack_w, dim3((4 * 512 * 512) / 256), dim3(256), 0, stream,
                     Wq, Wk, Wv, Wo, Bqkv_h, Bqkv_l, Bo_h, Bo_l);
  hipLaunchKernelGGL(pack_bias, dim3(6), dim3(256), 0, stream, bq, bk, bv, bias_qkv);

  hipLaunchKernelGGL(gemm_split, dim3(NQKV / BN, M_ROWS / BM), dim3(256), 0, stream,
                     Xh, Xl, Bqkv_h, Bqkv_l, bias_qkv, QKV, NQKV);

  hipLaunchKernelGGL(attn_win, dim3((M_ROWS * N_HEADS) / 4), dim3(256), 0, stream,
                     QKV, AOh, AOl);

  hipLaunchKernelGGL(gemm_split, dim3(D_MODEL / BN, M_ROWS / BM), dim3(256), 0, stream,
                     AOh, AOl, Bo_h, Bo_l, bo, out, D_MODEL);
}

// Round 2
// 151.388 us; speedup vs baseline: 1.3335x; 1.3335x over previous
//
#include <hip/hip_runtime.h>
#include <hip/hip_bf16.h>

typedef unsigned short u16;
typedef short bf16x8 __attribute__((ext_vector_type(8)));
typedef u16 u16x8 __attribute__((ext_vector_type(8)));
typedef float f32x4 __attribute__((ext_vector_type(4)));

#define D_MODEL 512
#define L_SEQ 2048
#define B_SZ 4
#define N_HEADS 8
#define D_K 64
#define M_ROWS (B_SZ * L_SEQ)   /* 8192 */
#define NQKV (3 * D_MODEL)      /* 1536 */
#define WIN 10
#define KDIM 512

__device__ inline u16 f2bf(float x) {
  __hip_bfloat16 h = __float2bfloat16(x);
  return *reinterpret_cast<u16*>(&h);
}
__device__ inline float bf2f(u16 u) {
  __hip_bfloat16 h;
  *reinterpret_cast<u16*>(&h) = u;
  return __bfloat162float(h);
}

// ---------------- pack X -> hi/lo bf16 ----------------
__global__ void pack_x(const float* __restrict__ X, u16* __restrict__ Xh,
                       u16* __restrict__ Xl, int n) {
  int i = blockIdx.x * blockDim.x + threadIdx.x;
  if (i >= n) return;
  float x = X[i];
  u16 hi = f2bf(x);
  u16 lo = f2bf(x - bf2f(hi));
  Xh[i] = hi;
  Xl[i] = lo;
}

// ---------------- pack weights transposed -> [N][K] hi/lo bf16 ----------------
__global__ void pack_w(const float* __restrict__ Wq, const float* __restrict__ Wk,
                       const float* __restrict__ Wv, const float* __restrict__ Wo,
                       u16* __restrict__ Bqkv_h, u16* __restrict__ Bqkv_l,
                       u16* __restrict__ Bo_h, u16* __restrict__ Bo_l) {
  int i = blockIdx.x * blockDim.x + threadIdx.x;  // 4*512*512
  int which = i >> 18;
  int r = i & 262143;
  int n = r >> 9;   // output col of W
  int k = r & 511;  // input dim
  const float* W = which == 0 ? Wq : which == 1 ? Wk : which == 2 ? Wv : Wo;
  float x = W[k * 512 + n];
  u16 hi = f2bf(x);
  u16 lo = f2bf(x - bf2f(hi));
  if (which < 3) {
    size_t o = ((size_t)(which * 512 + n)) * 512 + k;
    Bqkv_h[o] = hi; Bqkv_l[o] = lo;
  } else {
    size_t o = (size_t)n * 512 + k;
    Bo_h[o] = hi; Bo_l[o] = lo;
  }
}

__global__ void pack_bias(const float* __restrict__ bq, const float* __restrict__ bk,
                          const float* __restrict__ bv, float* __restrict__ bqkv) {
  int i = blockIdx.x * blockDim.x + threadIdx.x;
  if (i < 512) bqkv[i] = bq[i];
  else if (i < 1024) bqkv[i] = bk[i - 512];
  else if (i < 1536) bqkv[i] = bv[i - 1024];
}

// ---------------- split-bf16 GEMM: C[M][N] = A[M][K] * B[N][K]^T + bias ----------------
#define BM 128
#define BN 128
#define BK 32
#define LDK 40

__global__ __launch_bounds__(256) void gemm_split(
    const u16* __restrict__ Ah, const u16* __restrict__ Al,
    const u16* __restrict__ Bh, const u16* __restrict__ Bl,
    const float* __restrict__ bias, float* __restrict__ C, int N) {
  __shared__ u16 sAh[BM * LDK], sAl[BM * LDK], sBh[BN * LDK], sBl[BN * LDK];
  int t = threadIdx.x;
  int m0 = blockIdx.y * BM;
  int n0 = blockIdx.x * BN;
  int w = t >> 6, lane = t & 63;
  int wm = (w >> 1) * 64, wn = (w & 1) * 64;
  int fr = lane & 15, fo = (lane >> 4) * 8;

  f32x4 acc[4][4] = {};

  for (int kt = 0; kt < KDIM; kt += BK) {
    __syncthreads();
#pragma unroll
    for (int it = 0; it < 2; ++it) {
      int c = t + it * 256;
      int row = c >> 2;
      int col = (c & 3) << 3;
      size_t ga = (size_t)(m0 + row) * KDIM + kt + col;
      size_t gb = (size_t)(n0 + row) * KDIM + kt + col;
      *(u16x8*)&sAh[row * LDK + col] = *(const u16x8*)(Ah + ga);
      *(u16x8*)&sAl[row * LDK + col] = *(const u16x8*)(Al + ga);
      *(u16x8*)&sBh[row * LDK + col] = *(const u16x8*)(Bh + gb);
      *(u16x8*)&sBl[row * LDK + col] = *(const u16x8*)(Bl + gb);
    }
    __syncthreads();

    bf16x8 ah[4], al[4], bh[4], bl[4];
#pragma unroll
    for (int m = 0; m < 4; ++m) {
      int ar = wm + m * 16 + fr;
      ah[m] = *(const bf16x8*)&sAh[ar * LDK + fo];
      al[m] = *(const bf16x8*)&sAl[ar * LDK + fo];
      int br = wn + m * 16 + fr;
      bh[m] = *(const bf16x8*)&sBh[br * LDK + fo];
      bl[m] = *(const bf16x8*)&sBl[br * LDK + fo];
    }
#pragma unroll
    for (int m = 0; m < 4; ++m)
#pragma unroll
      for (int n = 0; n < 4; ++n) {
        acc[m][n] = __builtin_amdgcn_mfma_f32_16x16x32_bf16(ah[m], bh[n], acc[m][n], 0, 0, 0);
        acc[m][n] = __builtin_amdgcn_mfma_f32_16x16x32_bf16(ah[m], bl[n], acc[m][n], 0, 0, 0);
        acc[m][n] = __builtin_amdgcn_mfma_f32_16x16x32_bf16(al[m], bh[n], acc[m][n], 0, 0, 0);
      }
  }

  int rbase = m0 + wm + ((lane >> 4) << 2);
  int cbase = n0 + wn + fr;
#pragma unroll
  for (int n = 0; n < 4; ++n) {
    int cc = cbase + n * 16;
    float bn = bias[cc];
#pragma unroll
    for (int m = 0; m < 4; ++m) {
      int rr = rbase + m * 16;
#pragma unroll
      for (int q = 0; q < 4; ++q)
        C[(size_t)(rr + q) * N + cc] = acc[m][n][q] + bn;
    }
  }
}

// ---------------- windowed attention: diagonal (relative-offset) form ----------------
// One block per (b, h, 256-query l-tile). LDS holds Q^T [64][257] and K^T/V^T [64][277]
// (odd strides -> conflict-free transposed writes). lane <-> query l; for offset
// o in [0,20]: s[o] += Q[d][lane] * K[d][lane+o] — pure per-lane FMA, no shuffles.
#define ATILE 256
#define KROWS (ATILE + 2 * WIN)   /* 276 */
#define LQ 257
#define LK 277
#define ATTN_LDS ((64 * LQ + 64 * LK) * 4)  /* 136704 B */

__global__ __launch_bounds__(256) void attn_win(const float* __restrict__ QKV,
                                                u16* __restrict__ AOh,
                                                u16* __restrict__ AOl) {
  extern __shared__ float lds[];
  float* sQ = lds;            // [64][LQ]
  float* sK = lds + 64 * LQ;  // [64][LK], reused for V

  int t = threadIdx.x, w = t >> 6, lane = t & 63;
  int blk = blockIdx.x;
  int tile = blk & 7;
  int h = (blk >> 3) & 7;
  int b = blk >> 6;
  int l0 = tile * ATILE;
  const float* base = QKV + (size_t)b * L_SEQ * NQKV + h * D_K;

  // stage Q^T (rows l0..l0+255) and K^T (rows l0-10..l0+265, clamped)
  for (int i = w; i < ATILE; i += 4)
    sQ[lane * LQ + i] = base[(size_t)(l0 + i) * NQKV + lane];
  for (int i = w; i < KROWS; i += 4) {
    int l = l0 - WIN + i;
    l = min(max(l, 0), L_SEQ - 1);
    sK[lane * LK + i] = base[(size_t)l * NQKV + 512 + lane];
  }
  __syncthreads();

  int qcol = w * 64 + lane;       // query column within tile
  int myl = l0 + qcol;            // global l of this lane's query

  float s[21];
#pragma unroll
  for (int o = 0; o < 21; ++o) s[o] = 0.f;

  for (int d = 0; d < 64; ++d) {
    float qd = sQ[d * LQ + qcol];
#pragma unroll
    for (int o = 0; o < 21; ++o)
      s[o] += qd * sK[d * LK + qcol + o];
  }

  // per-lane softmax over valid offsets
  float m = -3.0e38f;
#pragma unroll
  for (int o = 0; o < 21; ++o) {
    int j = myl - WIN + o;
    float sv = fminf(fmaxf(s[o] * 0.125f, -10000.f), 10000.f);
    s[o] = (j >= 0 && j < L_SEQ) ? sv : -3.0e38f;
    m = fmaxf(m, s[o]);
  }
  float lsum = 0.f;
#pragma unroll
  for (int o = 0; o < 21; ++o) {
    float e = (s[o] > -1.0e37f) ? __expf(s[o] - m) : 0.f;
    s[o] = e;
    lsum += e;
  }
  float inv = 1.f / lsum;

  __syncthreads();
  // stage V^T over the K buffer
  for (int i = w; i < KROWS; i += 4) {
    int l = l0 - WIN + i;
    l = min(max(l, 0), L_SEQ - 1);
    sK[lane * LK + i] = base[(size_t)l * NQKV + 1024 + lane];
  }
  __syncthreads();

  // PV: out[d] = sum_o p[o] * V[d][qcol+o], emitted in 8-d chunks as bf16 hi/lo
  size_t orow = ((size_t)(b * L_SEQ + myl)) * D_MODEL + h * D_K;
#pragma unroll
  for (int g = 0; g < 8; ++g) {
    u16x8 hi8, lo8;
#pragma unroll
    for (int dd = 0; dd < 8; ++dd) {
      int d = g * 8 + dd;
      float a = 0.f;
#pragma unroll
      for (int o = 0; o < 21; ++o)
        a += s[o] * sK[d * LK + qcol + o];
      a *= inv;
      u16 hh = f2bf(a);
      hi8[dd] = hh;
      lo8[dd] = f2bf(a - bf2f(hh));
    }
    *(u16x8*)(AOh + orow + g * 8) = hi8;
    *(u16x8*)(AOl + orow + g * 8) = lo8;
  }
}

extern "C" void kernel_launch(void* const* d_in, const int* in_sizes, int n_in,
                              void* d_out, int out_size, void* d_ws, size_t ws_size,
                              hipStream_t stream) {
  const float* Q  = (const float*)d_in[0];
  const float* Wq = (const float*)d_in[1];
  const float* bq = (const float*)d_in[2];
  const float* Wk = (const float*)d_in[3];
  const float* bk = (const float*)d_in[4];
  const float* Wv = (const float*)d_in[5];
  const float* bv = (const float*)d_in[6];
  const float* Wo = (const float*)d_in[7];
  const float* bo = (const float*)d_in[8];
  float* out = (float*)d_out;

  char* p = (char*)d_ws;
  u16* Xh = (u16*)p;       p += (size_t)M_ROWS * 512 * 2;
  u16* Xl = (u16*)p;       p += (size_t)M_ROWS * 512 * 2;
  u16* Bqkv_h = (u16*)p;   p += (size_t)1536 * 512 * 2;
  u16* Bqkv_l = (u16*)p;   p += (size_t)1536 * 512 * 2;
  u16* Bo_h = (u16*)p;     p += (size_t)512 * 512 * 2;
  u16* Bo_l = (u16*)p;     p += (size_t)512 * 512 * 2;
  float* bias_qkv = (float*)p; p += 1536 * 4;
  float* QKV = (float*)p;  p += (size_t)M_ROWS * 1536 * 4;
  u16* AOh = (u16*)p;      p += (size_t)M_ROWS * 512 * 2;
  u16* AOl = (u16*)p;      p += (size_t)M_ROWS * 512 * 2;

  hipFuncSetAttribute((const void*)attn_win,
                      hipFuncAttributeMaxDynamicSharedMemorySize, ATTN_LDS);

  hipLaunchKernelGGL(pack_x, dim3((M_ROWS * 512) / 256), dim3(256), 0, stream,
                     Q, Xh, Xl, M_ROWS * 512);
  hipLaunchKernelGGL(pack_w, dim3((4 * 512 * 512) / 256), dim3(256), 0, stream,
                     Wq, Wk, Wv, Wo, Bqkv_h, Bqkv_l, Bo_h, Bo_l);
  hipLaunchKernelGGL(pack_bias, dim3(6), dim3(256), 0, stream, bq, bk, bv, bias_qkv);

  hipLaunchKernelGGL(gemm_split, dim3(NQKV / BN, M_ROWS / BM), dim3(256), 0, stream,
                     Xh, Xl, Bqkv_h, Bqkv_l, bias_qkv, QKV, NQKV);

  hipLaunchKernelGGL(attn_win, dim3(B_SZ * N_HEADS * (L_SEQ / ATILE)), dim3(256),
                     ATTN_LDS, stream, QKV, AOh, AOl);

  hipLaunchKernelGGL(gemm_split, dim3(D_MODEL / BN, M_ROWS / BM), dim3(256), 0, stream,
                     AOh, AOl, Bo_h, Bo_l, bo, out, D_MODEL);
}

// Round 3
// 106.291 us; speedup vs baseline: 1.8993x; 1.4243x over previous
//
#include <hip/hip_runtime.h>
#include <hip/hip_bf16.h>

typedef unsigned short u16;
typedef short bf16x8 __attribute__((ext_vector_type(8)));
typedef u16 u16x8 __attribute__((ext_vector_type(8)));
typedef u16 u16x4 __attribute__((ext_vector_type(4)));
typedef float f32x4 __attribute__((ext_vector_type(4)));

#define D_MODEL 512
#define L_SEQ 2048
#define B_SZ 4
#define N_HEADS 8
#define D_K 64
#define M_ROWS (B_SZ * L_SEQ)   /* 8192 */
#define NQKV (3 * D_MODEL)      /* 1536 */
#define WIN 10
#define KDIM 512

__device__ inline u16 f2bf(float x) {
  __hip_bfloat16 h = __float2bfloat16(x);
  return *reinterpret_cast<u16*>(&h);
}
__device__ inline float bf2f(u16 u) {
  __hip_bfloat16 h;
  *reinterpret_cast<u16*>(&h) = u;
  return __bfloat162float(h);
}

// ---------------- pack X -> hi bf16 only (2-term split keeps A in bf16) -------
__global__ void pack_x(const float* __restrict__ X, u16* __restrict__ Xh, int n4) {
  int i = blockIdx.x * blockDim.x + threadIdx.x;
  if (i >= n4) return;
  float4 x = ((const float4*)X)[i];
  u16x4 o;
  o[0] = f2bf(x.x); o[1] = f2bf(x.y); o[2] = f2bf(x.z); o[3] = f2bf(x.w);
  *(u16x4*)(Xh + i * 4) = o;
}

// ---------------- pack weights transposed -> [N][K] hi/lo bf16 ----------------
__global__ void pack_w(const float* __restrict__ Wq, const float* __restrict__ Wk,
                       const float* __restrict__ Wv, const float* __restrict__ Wo,
                       u16* __restrict__ Bqkv_h, u16* __restrict__ Bqkv_l,
                       u16* __restrict__ Bo_h, u16* __restrict__ Bo_l) {
  int i = blockIdx.x * blockDim.x + threadIdx.x;  // 4*512*512
  int which = i >> 18;
  int r = i & 262143;
  int n = r >> 9;   // output col of W
  int k = r & 511;  // input dim
  const float* W = which == 0 ? Wq : which == 1 ? Wk : which == 2 ? Wv : Wo;
  float x = W[k * 512 + n];
  u16 hi = f2bf(x);
  u16 lo = f2bf(x - bf2f(hi));
  if (which < 3) {
    size_t o = ((size_t)(which * 512 + n)) * 512 + k;
    Bqkv_h[o] = hi; Bqkv_l[o] = lo;
  } else {
    size_t o = (size_t)n * 512 + k;
    Bo_h[o] = hi; Bo_l[o] = lo;
  }
}

__global__ void pack_bias(const float* __restrict__ bq, const float* __restrict__ bk,
                          const float* __restrict__ bv, float* __restrict__ bqkv) {
  int i = blockIdx.x * blockDim.x + threadIdx.x;
  if (i < 512) bqkv[i] = bq[i];
  else if (i < 1024) bqkv[i] = bk[i - 512];
  else if (i < 1536) bqkv[i] = bv[i - 1024];
}

// ------- 2-term split GEMM: C = Ah * (Bh + Bl)^T + bias;  A bf16, B fp32-split
#define BM 128
#define BN 128
#define BK 32
#define LDK 40

__global__ __launch_bounds__(256) void gemm_split(
    const u16* __restrict__ Ah,
    const u16* __restrict__ Bh, const u16* __restrict__ Bl,
    const float* __restrict__ bias, float* __restrict__ C, int N) {
  __shared__ u16 sAh[BM * LDK], sBh[BN * LDK], sBl[BN * LDK];
  int t = threadIdx.x;
  int m0 = blockIdx.y * BM;
  int n0 = blockIdx.x * BN;
  int w = t >> 6, lane = t & 63;
  int wm = (w >> 1) * 64, wn = (w & 1) * 64;
  int fr = lane & 15, fo = (lane >> 4) * 8;

  f32x4 acc[4][4] = {};

  for (int kt = 0; kt < KDIM; kt += BK) {
    __syncthreads();
#pragma unroll
    for (int it = 0; it < 2; ++it) {
      int c = t + it * 256;
      int row = c >> 2;
      int col = (c & 3) << 3;
      size_t ga = (size_t)(m0 + row) * KDIM + kt + col;
      size_t gb = (size_t)(n0 + row) * KDIM + kt + col;
      *(u16x8*)&sAh[row * LDK + col] = *(const u16x8*)(Ah + ga);
      *(u16x8*)&sBh[row * LDK + col] = *(const u16x8*)(Bh + gb);
      *(u16x8*)&sBl[row * LDK + col] = *(const u16x8*)(Bl + gb);
    }
    __syncthreads();

    bf16x8 ah[4], bh[4], bl[4];
#pragma unroll
    for (int m = 0; m < 4; ++m) {
      int ar = wm + m * 16 + fr;
      ah[m] = *(const bf16x8*)&sAh[ar * LDK + fo];
      int br = wn + m * 16 + fr;
      bh[m] = *(const bf16x8*)&sBh[br * LDK + fo];
      bl[m] = *(const bf16x8*)&sBl[br * LDK + fo];
    }
#pragma unroll
    for (int m = 0; m < 4; ++m)
#pragma unroll
      for (int n = 0; n < 4; ++n) {
        acc[m][n] = __builtin_amdgcn_mfma_f32_16x16x32_bf16(ah[m], bh[n], acc[m][n], 0, 0, 0);
        acc[m][n] = __builtin_amdgcn_mfma_f32_16x16x32_bf16(ah[m], bl[n], acc[m][n], 0, 0, 0);
      }
  }

  int rbase = m0 + wm + ((lane >> 4) << 2);
  int cbase = n0 + wn + fr;
#pragma unroll
  for (int n = 0; n < 4; ++n) {
    int cc = cbase + n * 16;
    float bn = bias[cc];
#pragma unroll
    for (int m = 0; m < 4; ++m) {
      int rr = rbase + m * 16;
#pragma unroll
      for (int q = 0; q < 4; ++q)
        C[(size_t)(rr + q) * N + cc] = acc[m][n][q] + bn;
    }
  }
}

// ---------------- windowed attention: diagonal form, ATILE=128 ----------------
// Block = 256 thr = 4 waves; wave w owns queries w*32..w*32+31; lane = (q, d-half).
// LDS: Q^T [64][133] + K^T/V^T [64][149] fp32 = 72.2 KB -> 2 blocks/CU.
// Per (q,d-half): s[o] += Q[d][q] * K[d][q+o] (per-lane FMA); halves combined
// with one __shfl_xor(s,32); softmax per-lane; PV writes bf16-hi only.
#define ATILE 128
#define KROWS (ATILE + 2 * WIN)   /* 148 */
#define LQ 133
#define LK 149
#define ATTN_LDS ((64 * LQ + 64 * LK) * 4)  /* 72192 B */

__global__ __launch_bounds__(256) void attn_win(const float* __restrict__ QKV,
                                                u16* __restrict__ AOh) {
  extern __shared__ float lds[];
  float* sQ = lds;            // [64][LQ]
  float* sK = lds + 64 * LQ;  // [64][LK], reused for V

  int t = threadIdx.x;
  int blk = blockIdx.x;
  int tile = blk & 15;
  int h = (blk >> 4) & 7;
  int b = blk >> 7;
  int l0 = tile * ATILE;
  const float* base = QKV + (size_t)b * L_SEQ * NQKV + h * D_K;

  int kq = t & 15;   // d-quad index
  int ir = t >> 4;   // row slice

  // stage Q^T: 128 rows x 64 d, float4 along d, transposed scatter (2-way banks)
#pragma unroll
  for (int p = 0; p < 8; ++p) {
    int i = ir + p * 16;
    float4 g = *(const float4*)(base + (size_t)(l0 + i) * NQKV + kq * 4);
    sQ[(4 * kq + 0) * LQ + i] = g.x;
    sQ[(4 * kq + 1) * LQ + i] = g.y;
    sQ[(4 * kq + 2) * LQ + i] = g.z;
    sQ[(4 * kq + 3) * LQ + i] = g.w;
  }
  // stage K^T: 148 rows (clamped), cols +512
#pragma unroll
  for (int p = 0; p < 10; ++p) {
    int i = ir + p * 16;
    if (i < KROWS) {
      int l = min(max(l0 - WIN + i, 0), L_SEQ - 1);
      float4 g = *(const float4*)(base + (size_t)l * NQKV + 512 + kq * 4);
      sK[(4 * kq + 0) * LK + i] = g.x;
      sK[(4 * kq + 1) * LK + i] = g.y;
      sK[(4 * kq + 2) * LK + i] = g.z;
      sK[(4 * kq + 3) * LK + i] = g.w;
    }
  }
  __syncthreads();

  int w = t >> 6, lane = t & 63;
  int qloc = w * 32 + (lane & 31);
  int dbase = (lane >> 5) * 32;
  int myl = l0 + qloc;

  float s[21];
#pragma unroll
  for (int o = 0; o < 21; ++o) s[o] = 0.f;

  for (int d = 0; d < 32; ++d) {
    float qd = sQ[(dbase + d) * LQ + qloc];
    const float* kr = &sK[(dbase + d) * LK + qloc];
#pragma unroll
    for (int o = 0; o < 21; ++o)
      s[o] += qd * kr[o];
  }
  // combine d-halves
#pragma unroll
  for (int o = 0; o < 21; ++o) s[o] += __shfl_xor(s[o], 32);

  // per-lane softmax (both halves compute identically)
  float m = -3.0e38f;
#pragma unroll
  for (int o = 0; o < 21; ++o) {
    int j = myl - WIN + o;
    float sv = fminf(fmaxf(s[o] * 0.125f, -10000.f), 10000.f);
    s[o] = (j >= 0 && j < L_SEQ) ? sv : -3.0e38f;
    m = fmaxf(m, s[o]);
  }
  float lsum = 0.f;
#pragma unroll
  for (int o = 0; o < 21; ++o) {
    float e = (s[o] > -1.0e37f) ? __expf(s[o] - m) : 0.f;
    s[o] = e;
    lsum += e;
  }
  float inv = 1.f / lsum;

  __syncthreads();
  // stage V^T over sK
#pragma unroll
  for (int p = 0; p < 10; ++p) {
    int i = ir + p * 16;
    if (i < KROWS) {
      int l = min(max(l0 - WIN + i, 0), L_SEQ - 1);
      float4 g = *(const float4*)(base + (size_t)l * NQKV + 1024 + kq * 4);
      sK[(4 * kq + 0) * LK + i] = g.x;
      sK[(4 * kq + 1) * LK + i] = g.y;
      sK[(4 * kq + 2) * LK + i] = g.z;
      sK[(4 * kq + 3) * LK + i] = g.w;
    }
  }
  __syncthreads();

  // PV over this lane's d-half; each lane emits a contiguous 64B hi-bf16 run
  size_t orow = ((size_t)(b * L_SEQ + myl)) * D_MODEL + h * D_K + dbase;
#pragma unroll
  for (int g8 = 0; g8 < 4; ++g8) {
    u16x8 hi8;
#pragma unroll
    for (int dd = 0; dd < 8; ++dd) {
      int d = dbase + g8 * 8 + dd;
      const float* vr = &sK[d * LK + qloc];
      float a = 0.f;
#pragma unroll
      for (int o = 0; o < 21; ++o)
        a += s[o] * vr[o];
      hi8[dd] = f2bf(a * inv);
    }
    *(u16x8*)(AOh + orow + g8 * 8) = hi8;
  }
}

extern "C" void kernel_launch(void* const* d_in, const int* in_sizes, int n_in,
                              void* d_out, int out_size, void* d_ws, size_t ws_size,
                              hipStream_t stream) {
  const float* Q  = (const float*)d_in[0];
  const float* Wq = (const float*)d_in[1];
  const float* bq = (const float*)d_in[2];
  const float* Wk = (const float*)d_in[3];
  const float* bk = (const float*)d_in[4];
  const float* Wv = (const float*)d_in[5];
  const float* bv = (const float*)d_in[6];
  const float* Wo = (const float*)d_in[7];
  const float* bo = (const float*)d_in[8];
  float* out = (float*)d_out;

  char* p = (char*)d_ws;
  u16* Xh = (u16*)p;       p += (size_t)M_ROWS * 512 * 2;
  u16* Bqkv_h = (u16*)p;   p += (size_t)1536 * 512 * 2;
  u16* Bqkv_l = (u16*)p;   p += (size_t)1536 * 512 * 2;
  u16* Bo_h = (u16*)p;     p += (size_t)512 * 512 * 2;
  u16* Bo_l = (u16*)p;     p += (size_t)512 * 512 * 2;
  float* bias_qkv = (float*)p; p += 1536 * 4;
  float* QKV = (float*)p;  p += (size_t)M_ROWS * 1536 * 4;
  u16* AOh = (u16*)p;      p += (size_t)M_ROWS * 512 * 2;

  hipFuncSetAttribute((const void*)attn_win,
                      hipFuncAttributeMaxDynamicSharedMemorySize, ATTN_LDS);

  hipLaunchKernelGGL(pack_x, dim3((M_ROWS * 512 / 4) / 256), dim3(256), 0, stream,
                     Q, Xh, M_ROWS * 512 / 4);
  hipLaunchKernelGGL(pack_w, dim3((4 * 512 * 512) / 256), dim3(256), 0, stream,
                     Wq, Wk, Wv, Wo, Bqkv_h, Bqkv_l, Bo_h, Bo_l);
  hipLaunchKernelGGL(pack_bias, dim3(6), dim3(256), 0, stream, bq, bk, bv, bias_qkv);

  hipLaunchKernelGGL(gemm_split, dim3(NQKV / BN, M_ROWS / BM), dim3(256), 0, stream,
                     Xh, Bqkv_h, Bqkv_l, bias_qkv, QKV, NQKV);

  hipLaunchKernelGGL(attn_win, dim3(B_SZ * N_HEADS * (L_SEQ / ATILE)), dim3(256),
                     ATTN_LDS, stream, QKV, AOh);

  hipLaunchKernelGGL(gemm_split, dim3(D_MODEL / BN, M_ROWS / BM), dim3(256), 0, stream,
                     AOh, Bo_h, Bo_l, bo, out, D_MODEL);
}

// Round 4
// 102.981 us; speedup vs baseline: 1.9604x; 1.0321x over previous
//
#include <hip/hip_runtime.h>
#include <hip/hip_bf16.h>

typedef unsigned short u16;
typedef short bf16x8 __attribute__((ext_vector_type(8)));
typedef u16 u16x8 __attribute__((ext_vector_type(8)));
typedef u16 u16x4 __attribute__((ext_vector_type(4)));
typedef float f32x4 __attribute__((ext_vector_type(4)));

#define D_MODEL 512
#define L_SEQ 2048
#define B_SZ 4
#define N_HEADS 8
#define D_K 64
#define M_ROWS (B_SZ * L_SEQ)   /* 8192 */
#define NQKV (3 * D_MODEL)      /* 1536 */
#define WIN 10
#define KDIM 512

__device__ inline u16 f2bf(float x) {
  __hip_bfloat16 h = __float2bfloat16(x);
  return *reinterpret_cast<u16*>(&h);
}
__device__ inline float bf2f(u16 u) {
  __hip_bfloat16 h;
  *reinterpret_cast<u16*>(&h) = u;
  return __bfloat162float(h);
}

// async global->LDS, 16B per lane; LDS dest = uniform base + lane*16 (HW)
__device__ inline void stage16(const void* gptr, void* ldsptr) {
  void* g = const_cast<void*>(gptr);
  __builtin_amdgcn_global_load_lds(
      (__attribute__((address_space(1))) void*)g,
      (__attribute__((address_space(3))) void*)ldsptr, 16, 0, 0);
}

// ---------------- pack X -> bf16 ----------------
__global__ void pack_x(const float* __restrict__ X, u16* __restrict__ Xh, int n4) {
  int i = blockIdx.x * blockDim.x + threadIdx.x;
  if (i >= n4) return;
  float4 x = ((const float4*)X)[i];
  u16x4 o;
  o[0] = f2bf(x.x); o[1] = f2bf(x.y); o[2] = f2bf(x.z); o[3] = f2bf(x.w);
  *(u16x4*)(Xh + i * 4) = o;
}

// ---------------- pack weights transposed -> [N][K] hi/lo bf16 ----------------
__global__ void pack_w(const float* __restrict__ Wq, const float* __restrict__ Wk,
                       const float* __restrict__ Wv, const float* __restrict__ Wo,
                       u16* __restrict__ Bqkv_h, u16* __restrict__ Bqkv_l,
                       u16* __restrict__ Bo_h, u16* __restrict__ Bo_l) {
  int i = blockIdx.x * blockDim.x + threadIdx.x;  // 4*512*512
  int which = i >> 18;
  int r = i & 262143;
  int n = r >> 9;
  int k = r & 511;
  const float* W = which == 0 ? Wq : which == 1 ? Wk : which == 2 ? Wv : Wo;
  float x = W[k * 512 + n];
  u16 hi = f2bf(x);
  u16 lo = f2bf(x - bf2f(hi));
  if (which < 3) {
    size_t o = ((size_t)(which * 512 + n)) * 512 + k;
    Bqkv_h[o] = hi; Bqkv_l[o] = lo;
  } else {
    size_t o = (size_t)n * 512 + k;
    Bo_h[o] = hi; Bo_l[o] = lo;
  }
}

__global__ void pack_bias(const float* __restrict__ bq, const float* __restrict__ bk,
                          const float* __restrict__ bv, float* __restrict__ bqkv) {
  int i = blockIdx.x * blockDim.x + threadIdx.x;
  if (i < 512) bqkv[i] = bq[i];
  else if (i < 1024) bqkv[i] = bk[i - 512];
  else if (i < 1536) bqkv[i] = bv[i - 1024];
}

// ------- m97-structure 2-term split GEMM: C = A * (Bh+Bl)^T + bias ----------
// BK=32, linear LDS [rows][32] bf16 (64B rows), global_load_lds width-16
// staging (1KB chunk = 16 rows), 2-barrier K-loop. OUTBF: write bf16 else f32.
template <int BM, int BN, int MFR, int NFR, int OUTBF>
__global__ __launch_bounds__(256) void gemm_gl(
    const u16* __restrict__ A,
    const u16* __restrict__ Bh, const u16* __restrict__ Bl,
    const float* __restrict__ bias, void* __restrict__ Cv, int N) {
  constexpr int BK = 32;
  constexpr int CA = BM * BK * 2 / 1024;  // 1KB chunks in A tile
  constexpr int CB = BN * BK * 2 / 1024;
  __shared__ u16 sA[BM * BK], sBh[BN * BK], sBl[BN * BK];

  int t = threadIdx.x;
  int w = t >> 6, lane = t & 63;
  int m0 = blockIdx.y * BM, n0 = blockIdx.x * BN;
  constexpr int NWN = BN / (NFR * 16);
  int wm = (w / NWN) * MFR * 16;
  int wn = (w % NWN) * NFR * 16;
  int fr = lane & 15, fo = lane >> 4;

  int rl = lane >> 2;           // row within 16-row chunk
  int cbyte = (lane & 3) * 16;  // byte col within 64B row
  const char* Ab = (const char*)A;
  const char* Bhb = (const char*)Bh;
  const char* Blb = (const char*)Bl;

  f32x4 acc[MFR][NFR] = {};

  for (int kt = 0; kt < KDIM; kt += BK) {
    // ---- stage via global_load_lds (per-wave chunks) ----
#pragma unroll
    for (int c = w; c < CA; c += 4) {
      int row = c * 16 + rl;
      stage16(Ab + ((size_t)(m0 + row) * KDIM + kt) * 2 + cbyte,
              (char*)sA + c * 1024);
    }
#pragma unroll
    for (int c = w; c < CB; c += 4) {
      int row = c * 16 + rl;
      stage16(Bhb + ((size_t)(n0 + row) * KDIM + kt) * 2 + cbyte,
              (char*)sBh + c * 1024);
      stage16(Blb + ((size_t)(n0 + row) * KDIM + kt) * 2 + cbyte,
              (char*)sBl + c * 1024);
    }
    __syncthreads();  // drains vmcnt(0): staged data visible

    bf16x8 af[MFR], bhf[NFR], blf[NFR];
#pragma unroll
    for (int m = 0; m < MFR; ++m)
      af[m] = *(const bf16x8*)&sA[(wm + m * 16 + fr) * BK + fo * 8];
#pragma unroll
    for (int n = 0; n < NFR; ++n) {
      bhf[n] = *(const bf16x8*)&sBh[(wn + n * 16 + fr) * BK + fo * 8];
      blf[n] = *(const bf16x8*)&sBl[(wn + n * 16 + fr) * BK + fo * 8];
    }
#pragma unroll
    for (int m = 0; m < MFR; ++m)
#pragma unroll
      for (int n = 0; n < NFR; ++n) {
        acc[m][n] = __builtin_amdgcn_mfma_f32_16x16x32_bf16(af[m], bhf[n], acc[m][n], 0, 0, 0);
        acc[m][n] = __builtin_amdgcn_mfma_f32_16x16x32_bf16(af[m], blf[n], acc[m][n], 0, 0, 0);
      }
    __syncthreads();  // protect LDS before next stage overwrites
  }

  // epilogue: C/D frag col = lane&15, row = 4*(lane>>4) + q
  int rbase = m0 + wm + fo * 4;
  int cbase = n0 + wn + fr;
#pragma unroll
  for (int n = 0; n < NFR; ++n) {
    int cc = cbase + n * 16;
    float bn = bias[cc];
#pragma unroll
    for (int m = 0; m < MFR; ++m) {
      int rr = rbase + m * 16;
#pragma unroll
      for (int q = 0; q < 4; ++q) {
        float v = acc[m][n][q] + bn;
        if (OUTBF)
          ((u16*)Cv)[(size_t)(rr + q) * N + cc] = f2bf(v);
        else
          ((float*)Cv)[(size_t)(rr + q) * N + cc] = v;
      }
    }
  }
}

// ---------------- windowed attention: diagonal form, bf16 QKV in ----------------
#define ATILE 128
#define KROWS (ATILE + 2 * WIN)   /* 148 */
#define LQ 133
#define LK 149
#define ATTN_LDS ((64 * LQ + 64 * LK) * 4)  /* 72192 B */

__global__ __launch_bounds__(256) void attn_win(const u16* __restrict__ QKV,
                                                u16* __restrict__ AOh) {
  extern __shared__ float lds[];
  float* sQ = lds;            // [64][LQ]
  float* sK = lds + 64 * LQ;  // [64][LK], reused for V

  int t = threadIdx.x;
  int blk = blockIdx.x;
  int tile = blk & 15;
  int h = (blk >> 4) & 7;
  int b = blk >> 7;
  int l0 = tile * ATILE;
  const u16* base = QKV + (size_t)b * L_SEQ * NQKV + h * D_K;

  int kq = t & 7;   // 8-d chunk index (8 chunks x 8 d = 64)
  int ir = t >> 3;  // 32 rows per pass

  // stage Q^T: 128 rows
#pragma unroll
  for (int p = 0; p < 4; ++p) {
    int i = ir + p * 32;
    u16x8 g = *(const u16x8*)(base + (size_t)(l0 + i) * NQKV + kq * 8);
#pragma unroll
    for (int e = 0; e < 8; ++e)
      sQ[(8 * kq + e) * LQ + i] = bf2f(g[e]);
  }
  // stage K^T: 148 rows (clamped)
#pragma unroll
  for (int p = 0; p < 5; ++p) {
    int i = ir + p * 32;
    if (i < KROWS) {
      int l = min(max(l0 - WIN + i, 0), L_SEQ - 1);
      u16x8 g = *(const u16x8*)(base + (size_t)l * NQKV + 512 + kq * 8);
#pragma unroll
      for (int e = 0; e < 8; ++e)
        sK[(8 * kq + e) * LK + i] = bf2f(g[e]);
    }
  }
  __syncthreads();

  int w = t >> 6, lane = t & 63;
  int qloc = w * 32 + (lane & 31);
  int dbase = (lane >> 5) * 32;
  int myl = l0 + qloc;

  float s[21];
#pragma unroll
  for (int o = 0; o < 21; ++o) s[o] = 0.f;

  for (int d = 0; d < 32; ++d) {
    float qd = sQ[(dbase + d) * LQ + qloc];
    const float* kr = &sK[(dbase + d) * LK + qloc];
#pragma unroll
    for (int o = 0; o < 21; ++o)
      s[o] += qd * kr[o];
  }
#pragma unroll
  for (int o = 0; o < 21; ++o) s[o] += __shfl_xor(s[o], 32);

  float m = -3.0e38f;
#pragma unroll
  for (int o = 0; o < 21; ++o) {
    int j = myl - WIN + o;
    float sv = fminf(fmaxf(s[o] * 0.125f, -10000.f), 10000.f);
    s[o] = (j >= 0 && j < L_SEQ) ? sv : -3.0e38f;
    m = fmaxf(m, s[o]);
  }
  float lsum = 0.f;
#pragma unroll
  for (int o = 0; o < 21; ++o) {
    float e = (s[o] > -1.0e37f) ? __expf(s[o] - m) : 0.f;
    s[o] = e;
    lsum += e;
  }
  float inv = 1.f / lsum;

  __syncthreads();
  // stage V^T over sK
#pragma unroll
  for (int p = 0; p < 5; ++p) {
    int i = ir + p * 32;
    if (i < KROWS) {
      int l = min(max(l0 - WIN + i, 0), L_SEQ - 1);
      u16x8 g = *(const u16x8*)(base + (size_t)l * NQKV + 1024 + kq * 8);
#pragma unroll
      for (int e = 0; e < 8; ++e)
        sK[(8 * kq + e) * LK + i] = bf2f(g[e]);
    }
  }
  __syncthreads();

  size_t orow = ((size_t)(b * L_SEQ + myl)) * D_MODEL + h * D_K + dbase;
#pragma unroll
  for (int g8 = 0; g8 < 4; ++g8) {
    u16x8 hi8;
#pragma unroll
    for (int dd = 0; dd < 8; ++dd) {
      int d = dbase + g8 * 8 + dd;
      const float* vr = &sK[d * LK + qloc];
      float a = 0.f;
#pragma unroll
      for (int o = 0; o < 21; ++o)
        a += s[o] * vr[o];
      hi8[dd] = f2bf(a * inv);
    }
    *(u16x8*)(AOh + orow + g8 * 8) = hi8;
  }
}

extern "C" void kernel_launch(void* const* d_in, const int* in_sizes, int n_in,
                              void* d_out, int out_size, void* d_ws, size_t ws_size,
                              hipStream_t stream) {
  const float* Q  = (const float*)d_in[0];
  const float* Wq = (const float*)d_in[1];
  const float* bq = (const float*)d_in[2];
  const float* Wk = (const float*)d_in[3];
  const float* bk = (const float*)d_in[4];
  const float* Wv = (const float*)d_in[5];
  const float* bv = (const float*)d_in[6];
  const float* Wo = (const float*)d_in[7];
  const float* bo = (const float*)d_in[8];
  float* out = (float*)d_out;

  char* p = (char*)d_ws;
  u16* Xh = (u16*)p;       p += (size_t)M_ROWS * 512 * 2;
  u16* Bqkv_h = (u16*)p;   p += (size_t)1536 * 512 * 2;
  u16* Bqkv_l = (u16*)p;   p += (size_t)1536 * 512 * 2;
  u16* Bo_h = (u16*)p;     p += (size_t)512 * 512 * 2;
  u16* Bo_l = (u16*)p;     p += (size_t)512 * 512 * 2;
  float* bias_qkv = (float*)p; p += 1536 * 4;
  u16* QKV = (u16*)p;      p += (size_t)M_ROWS * 1536 * 2;
  u16* AOh = (u16*)p;      p += (size_t)M_ROWS * 512 * 2;

  hipFuncSetAttribute((const void*)attn_win,
                      hipFuncAttributeMaxDynamicSharedMemorySize, ATTN_LDS);

  hipLaunchKernelGGL(pack_x, dim3((M_ROWS * 512 / 4) / 256), dim3(256), 0, stream,
                     Q, Xh, M_ROWS * 512 / 4);
  hipLaunchKernelGGL(pack_w, dim3((4 * 512 * 512) / 256), dim3(256), 0, stream,
                     Wq, Wk, Wv, Wo, Bqkv_h, Bqkv_l, Bo_h, Bo_l);
  hipLaunchKernelGGL(pack_bias, dim3(6), dim3(256), 0, stream, bq, bk, bv, bias_qkv);

  gemm_gl<128, 128, 4, 4, 1><<<dim3(NQKV / 128, M_ROWS / 128), 256, 0, stream>>>(
      Xh, Bqkv_h, Bqkv_l, bias_qkv, (void*)QKV, NQKV);

  hipLaunchKernelGGL(attn_win, dim3(B_SZ * N_HEADS * (L_SEQ / ATILE)), dim3(256),
                     ATTN_LDS, stream, QKV, AOh);

  gemm_gl<64, 64, 2, 2, 0><<<dim3(D_MODEL / 64, M_ROWS / 64), 256, 0, stream>>>(
      AOh, Bo_h, Bo_l, bo, (void*)out, D_MODEL);
}

// Round 5
// 101.728 us; speedup vs baseline: 1.9845x; 1.0123x over previous
//
#include <hip/hip_runtime.h>
#include <hip/hip_bf16.h>

typedef unsigned short u16;
typedef short bf16x8 __attribute__((ext_vector_type(8)));
typedef u16 u16x8 __attribute__((ext_vector_type(8)));
typedef u16 u16x4 __attribute__((ext_vector_type(4)));
typedef float f32x4 __attribute__((ext_vector_type(4)));

#define D_MODEL 512
#define L_SEQ 2048
#define B_SZ 4
#define N_HEADS 8
#define D_K 64
#define M_ROWS 8192
#define NQKV 1536
#define WIN 10
#define KDIM 512

__device__ inline u16 f2bf(float x) {
  __hip_bfloat16 h = __float2bfloat16(x);
  return *reinterpret_cast<u16*>(&h);
}
__device__ inline float bf2f(u16 u) {
  __hip_bfloat16 h;
  *reinterpret_cast<u16*>(&h) = u;
  return __bfloat162float(h);
}

// async global->LDS, 16B/lane; LDS dest = WAVE-UNIFORM base + lane*16 (HW)
__device__ inline void stage16(const void* gptr, void* ldsptr) {
  void* g = const_cast<void*>(gptr);
  __builtin_amdgcn_global_load_lds(
      (__attribute__((address_space(1))) void*)g,
      (__attribute__((address_space(3))) void*)ldsptr, 16, 0, 0);
}

#define VM4() asm volatile("s_waitcnt vmcnt(4)" ::: "memory")
#define BARX()                            \
  do {                                    \
    asm volatile("" ::: "memory");        \
    __builtin_amdgcn_s_barrier();         \
    asm volatile("" ::: "memory");        \
  } while (0)

// ---------------- pack X -> bf16 ----------------
__global__ void pack_x(const float* __restrict__ X, u16* __restrict__ Xh, int n4) {
  int i = blockIdx.x * blockDim.x + threadIdx.x;
  if (i >= n4) return;
  float4 x = ((const float4*)X)[i];
  u16x4 o;
  o[0] = f2bf(x.x); o[1] = f2bf(x.y); o[2] = f2bf(x.z); o[3] = f2bf(x.w);
  *(u16x4*)(Xh + i * 4) = o;
}

// ------- pack weights transposed, combined-K: [N][1024], cols 0-511 hi, 512-1023 lo
__global__ void pack_w(const float* __restrict__ Wq, const float* __restrict__ Wk,
                       const float* __restrict__ Wv, const float* __restrict__ Wo,
                       u16* __restrict__ Bqkv, u16* __restrict__ Bo) {
  int i = blockIdx.x * blockDim.x + threadIdx.x;  // 4*512*512
  int which = i >> 18;
  int r = i & 262143;
  int n = r >> 9;
  int k = r & 511;
  const float* W = which == 0 ? Wq : which == 1 ? Wk : which == 2 ? Wv : Wo;
  float x = W[k * 512 + n];
  u16 hi = f2bf(x);
  u16 lo = f2bf(x - bf2f(hi));
  if (which < 3) {
    size_t o = ((size_t)(which * 512 + n)) * 1024 + k;
    Bqkv[o] = hi; Bqkv[o + 512] = lo;
  } else {
    size_t o = (size_t)n * 1024 + k;
    Bo[o] = hi; Bo[o + 512] = lo;
  }
}

__global__ void pack_bias(const float* __restrict__ bq, const float* __restrict__ bk,
                          const float* __restrict__ bv, float* __restrict__ bqkv) {
  int i = blockIdx.x * blockDim.x + threadIdx.x;
  if (i < 512) bqkv[i] = bq[i];
  else if (i < 1024) bqkv[i] = bk[i - 512];
  else if (i < 1536) bqkv[i] = bv[i - 1024];
}

// ================= 8-phase 256x256 GEMM, combined K=1024 =================
// C[M][N] = A[M][512] x Bc[N][1024]^T (A re-read for both K halves) + bias.
// 8 waves as 2M x 4N, per-wave 128x64 INTERLEAVED across tile halves:
//   m-frags 0-3 in A0 (rows 0-127), 4-7 in A1; n-frags 0-1 in B0, 2-3 in B1.
// LDS: 2 buf x 4 half-tiles(16KB: [128 rows][64 k] bf16, 128B rows) = 128KB.
// Stage order per K-tile: P0:A0 P1:B0 P2:B1 P3:A1; consumption next tile:
//   P0:{A0,B0} P1:{B1} P2:{A1} -> uniform s_waitcnt vmcnt(4), never 0.
// T2 swizzle (rule 21): linear gload_lds dest, source slot s^(r&7), read slot
//   (ks*4+fo)^(fr&7) -> 2-way banks (free).
#define G8_LDS 131072

template <int PAIR>
__device__ inline void stage_pair(const char* Ab, const char* Bb, char* lds,
                                  long m0, long n0, int kt, int buf, int t, int w) {
  constexpr int off = PAIR == 0 ? 0 : PAIR == 3 ? 16384 : PAIR == 1 ? 32768 : 49152;
#pragma unroll
  for (int i = 0; i < 2; ++i) {
    int r = i * 64 + (t >> 3);
    int s = (t & 7) ^ (r & 7);
    const char* src;
    if (PAIR == 0 || PAIR == 3)
      src = Ab + ((m0 + (PAIR == 3 ? 128 : 0) + r) * 512 + (long)(kt & 7) * 64) * 2 + s * 16;
    else
      src = Bb + ((n0 + (PAIR == 2 ? 128 : 0) + r) * 1024 + (long)kt * 64) * 2 + s * 16;
    stage16(src, lds + buf * 65536 + off + i * 8192 + w * 1024);
  }
}

template <int OUTBF>
__global__ __launch_bounds__(512, 1) void gemm8p(
    const u16* __restrict__ A, const u16* __restrict__ Bc,
    const float* __restrict__ bias, void* __restrict__ Cv, int M, int N) {
  extern __shared__ char lds[];
  const int t = threadIdx.x;
  const int w = t >> 6, lane = t & 63;
  const int fr = lane & 15, fo = lane >> 4;

  // XCD-bijective swizzle (grid % 8 == 0), m-tiles fastest
  int nwg = gridDim.x, bid = blockIdx.x;
  int swz = (bid & 7) * (nwg >> 3) + (bid >> 3);
  int mtiles = M >> 8;
  long m0 = (long)(swz % mtiles) << 8;
  long n0 = (long)(swz / mtiles) << 8;

  const char* Ab = (const char*)A;
  const char* Bb = (const char*)Bc;

  auto LDA = [&](int buf, int mf, int ks) -> bf16x8 {
    int r = (w >> 2) * 64 + (mf & 3) * 16 + fr;
    return *(const bf16x8*)(lds + buf * 65536 + (mf >> 2) * 16384 + r * 128 +
                            (((ks * 4 + fo) ^ (fr & 7)) * 16));
  };
  auto LDB = [&](int buf, int nf, int ks) -> bf16x8 {
    int r = (w & 3) * 32 + (nf & 1) * 16 + fr;
    return *(const bf16x8*)(lds + buf * 65536 + 32768 + (nf >> 1) * 16384 + r * 128 +
                            (((ks * 4 + fo) ^ (fr & 7)) * 16));
  };

  f32x4 acc[8][4] = {};
  bf16x8 Af[4][2], Bf[4][2];

  // prologue: stage K-tile 0 into buf 0 (pairs in consumption order)
  stage_pair<0>(Ab, Bb, lds, m0, n0, 0, 0, t, w);
  stage_pair<1>(Ab, Bb, lds, m0, n0, 0, 0, t, w);
  stage_pair<2>(Ab, Bb, lds, m0, n0, 0, 0, t, w);
  stage_pair<3>(Ab, Bb, lds, m0, n0, 0, 0, t, w);

  for (int kt = 0; kt < 16; ++kt) {
    const int cur = kt & 1, nxt = cur ^ 1;
    const int kn = kt < 15 ? kt + 1 : 15;  // last tile re-stages itself (harmless)

    // ---- P0: needs A0,B0 of cur ----
    VM4();
    BARX();
#pragma unroll
    for (int mf = 0; mf < 4; ++mf) {
      Af[mf][0] = LDA(cur, mf, 0);
      Af[mf][1] = LDA(cur, mf, 1);
    }
#pragma unroll
    for (int nf = 0; nf < 2; ++nf) {
      Bf[nf][0] = LDB(cur, nf, 0);
      Bf[nf][1] = LDB(cur, nf, 1);
    }
    stage_pair<0>(Ab, Bb, lds, m0, n0, kn, nxt, t, w);
    __builtin_amdgcn_s_setprio(1);
#pragma unroll
    for (int mf = 0; mf < 4; ++mf)
#pragma unroll
      for (int nf = 0; nf < 2; ++nf) {
        acc[mf][nf] = __builtin_amdgcn_mfma_f32_16x16x32_bf16(Af[mf][0], Bf[nf][0], acc[mf][nf], 0, 0, 0);
        acc[mf][nf] = __builtin_amdgcn_mfma_f32_16x16x32_bf16(Af[mf][1], Bf[nf][1], acc[mf][nf], 0, 0, 0);
      }
    __builtin_amdgcn_s_setprio(0);

    // ---- P1: needs B1 of cur ----
    VM4();
    BARX();
#pragma unroll
    for (int nf = 2; nf < 4; ++nf) {
      Bf[nf][0] = LDB(cur, nf, 0);
      Bf[nf][1] = LDB(cur, nf, 1);
    }
    stage_pair<1>(Ab, Bb, lds, m0, n0, kn, nxt, t, w);
    __builtin_amdgcn_s_setprio(1);
#pragma unroll
    for (int mf = 0; mf < 4; ++mf)
#pragma unroll
      for (int nf = 2; nf < 4; ++nf) {
        acc[mf][nf] = __builtin_amdgcn_mfma_f32_16x16x32_bf16(Af[mf][0], Bf[nf][0], acc[mf][nf], 0, 0, 0);
        acc[mf][nf] = __builtin_amdgcn_mfma_f32_16x16x32_bf16(Af[mf][1], Bf[nf][1], acc[mf][nf], 0, 0, 0);
      }
    __builtin_amdgcn_s_setprio(0);

    // ---- P2: needs A1 of cur ----
    VM4();
    BARX();
#pragma unroll
    for (int mf = 0; mf < 4; ++mf) {
      Af[mf][0] = LDA(cur, mf + 4, 0);
      Af[mf][1] = LDA(cur, mf + 4, 1);
    }
    stage_pair<2>(Ab, Bb, lds, m0, n0, kn, nxt, t, w);
    __builtin_amdgcn_s_setprio(1);
#pragma unroll
    for (int mf = 0; mf < 4; ++mf)
#pragma unroll
      for (int nf = 2; nf < 4; ++nf) {
        acc[mf + 4][nf] = __builtin_amdgcn_mfma_f32_16x16x32_bf16(Af[mf][0], Bf[nf][0], acc[mf + 4][nf], 0, 0, 0);
        acc[mf + 4][nf] = __builtin_amdgcn_mfma_f32_16x16x32_bf16(Af[mf][1], Bf[nf][1], acc[mf + 4][nf], 0, 0, 0);
      }
    __builtin_amdgcn_s_setprio(0);

    // ---- P3: register-only compute (B0 held since P0); no wait/barrier ----
    stage_pair<3>(Ab, Bb, lds, m0, n0, kn, nxt, t, w);
    __builtin_amdgcn_s_setprio(1);
#pragma unroll
    for (int mf = 0; mf < 4; ++mf)
#pragma unroll
      for (int nf = 0; nf < 2; ++nf) {
        acc[mf + 4][nf] = __builtin_amdgcn_mfma_f32_16x16x32_bf16(Af[mf][0], Bf[nf][0], acc[mf + 4][nf], 0, 0, 0);
        acc[mf + 4][nf] = __builtin_amdgcn_mfma_f32_16x16x32_bf16(Af[mf][1], Bf[nf][1], acc[mf + 4][nf], 0, 0, 0);
      }
    __builtin_amdgcn_s_setprio(0);
  }

  // epilogue: C/D frag col = lane&15, row = 4*(lane>>4)+q (interleaved halves)
#pragma unroll
  for (int nf = 0; nf < 4; ++nf) {
    long col = n0 + (nf >> 1) * 128 + (w & 3) * 32 + (nf & 1) * 16 + fr;
    float bn = bias[col];
#pragma unroll
    for (int mf = 0; mf < 8; ++mf) {
      long row = m0 + (mf >> 2) * 128 + (w >> 2) * 64 + (mf & 3) * 16 + fo * 4;
#pragma unroll
      for (int q = 0; q < 4; ++q) {
        float v = acc[mf][nf][q] + bn;
        if (OUTBF)
          ((u16*)Cv)[(size_t)(row + q) * N + col] = f2bf(v);
        else
          ((float*)Cv)[(size_t)(row + q) * N + col] = v;
      }
    }
  }
}

// ---------------- windowed attention: diagonal form, bf16 QKV in ----------------
#define ATILE 128
#define KROWS (ATILE + 2 * WIN)   /* 148 */
#define LQ 133
#define LK 149
#define ATTN_LDS ((64 * LQ + 64 * LK) * 4)  /* 72192 B */

__global__ __launch_bounds__(256) void attn_win(const u16* __restrict__ QKV,
                                                u16* __restrict__ AOh) {
  extern __shared__ float flds[];
  float* sQ = flds;            // [64][LQ]
  float* sK = flds + 64 * LQ;  // [64][LK], reused for V

  int t = threadIdx.x;
  int blk = blockIdx.x;
  int tile = blk & 15;
  int h = (blk >> 4) & 7;
  int b = blk >> 7;
  int l0 = tile * ATILE;
  const u16* base = QKV + (size_t)b * L_SEQ * NQKV + h * D_K;

  int kq = t & 7;   // 8-d chunk index
  int ir = t >> 3;  // 32 rows per pass

#pragma unroll
  for (int p = 0; p < 4; ++p) {
    int i = ir + p * 32;
    u16x8 g = *(const u16x8*)(base + (size_t)(l0 + i) * NQKV + kq * 8);
#pragma unroll
    for (int e = 0; e < 8; ++e)
      sQ[(8 * kq + e) * LQ + i] = bf2f(g[e]);
  }
#pragma unroll
  for (int p = 0; p < 5; ++p) {
    int i = ir + p * 32;
    if (i < KROWS) {
      int l = min(max(l0 - WIN + i, 0), L_SEQ - 1);
      u16x8 g = *(const u16x8*)(base + (size_t)l * NQKV + 512 + kq * 8);
#pragma unroll
      for (int e = 0; e < 8; ++e)
        sK[(8 * kq + e) * LK + i] = bf2f(g[e]);
    }
  }
  __syncthreads();

  int w = t >> 6, lane = t & 63;
  int qloc = w * 32 + (lane & 31);
  int dbase = (lane >> 5) * 32;
  int myl = l0 + qloc;

  float s[21];
#pragma unroll
  for (int o = 0; o < 21; ++o) s[o] = 0.f;

  for (int d = 0; d < 32; ++d) {
    float qd = sQ[(dbase + d) * LQ + qloc];
    const float* kr = &sK[(dbase + d) * LK + qloc];
#pragma unroll
    for (int o = 0; o < 21; ++o)
      s[o] += qd * kr[o];
  }
#pragma unroll
  for (int o = 0; o < 21; ++o) s[o] += __shfl_xor(s[o], 32);

  float m = -3.0e38f;
#pragma unroll
  for (int o = 0; o < 21; ++o) {
    int j = myl - WIN + o;
    float sv = fminf(fmaxf(s[o] * 0.125f, -10000.f), 10000.f);
    s[o] = (j >= 0 && j < L_SEQ) ? sv : -3.0e38f;
    m = fmaxf(m, s[o]);
  }
  float lsum = 0.f;
#pragma unroll
  for (int o = 0; o < 21; ++o) {
    float e = (s[o] > -1.0e37f) ? __expf(s[o] - m) : 0.f;
    s[o] = e;
    lsum += e;
  }
  float inv = 1.f / lsum;

  __syncthreads();
#pragma unroll
  for (int p = 0; p < 5; ++p) {
    int i = ir + p * 32;
    if (i < KROWS) {
      int l = min(max(l0 - WIN + i, 0), L_SEQ - 1);
      u16x8 g = *(const u16x8*)(base + (size_t)l * NQKV + 1024 + kq * 8);
#pragma unroll
      for (int e = 0; e < 8; ++e)
        sK[(8 * kq + e) * LK + i] = bf2f(g[e]);
    }
  }
  __syncthreads();

  size_t orow = ((size_t)(b * L_SEQ + myl)) * D_MODEL + h * D_K + dbase;
#pragma unroll
  for (int g8 = 0; g8 < 4; ++g8) {
    u16x8 hi8;
#pragma unroll
    for (int dd = 0; dd < 8; ++dd) {
      int d = dbase + g8 * 8 + dd;
      const float* vr = &sK[d * LK + qloc];
      float a = 0.f;
#pragma unroll
      for (int o = 0; o < 21; ++o)
        a += s[o] * vr[o];
      hi8[dd] = f2bf(a * inv);
    }
    *(u16x8*)(AOh + orow + g8 * 8) = hi8;
  }
}

extern "C" void kernel_launch(void* const* d_in, const int* in_sizes, int n_in,
                              void* d_out, int out_size, void* d_ws, size_t ws_size,
                              hipStream_t stream) {
  const float* Q  = (const float*)d_in[0];
  const float* Wq = (const float*)d_in[1];
  const float* bq = (const float*)d_in[2];
  const float* Wk = (const float*)d_in[3];
  const float* bk = (const float*)d_in[4];
  const float* Wv = (const float*)d_in[5];
  const float* bv = (const float*)d_in[6];
  const float* Wo = (const float*)d_in[7];
  const float* bo = (const float*)d_in[8];
  float* out = (float*)d_out;

  char* p = (char*)d_ws;
  u16* Xh = (u16*)p;        p += (size_t)M_ROWS * 512 * 2;
  u16* Bqkv = (u16*)p;      p += (size_t)1536 * 1024 * 2;
  u16* Bo = (u16*)p;        p += (size_t)512 * 1024 * 2;
  float* bias_qkv = (float*)p; p += 1536 * 4;
  u16* QKV = (u16*)p;       p += (size_t)M_ROWS * 1536 * 2;
  u16* AOh = (u16*)p;       p += (size_t)M_ROWS * 512 * 2;

  hipFuncSetAttribute((const void*)attn_win,
                      hipFuncAttributeMaxDynamicSharedMemorySize, ATTN_LDS);
  hipFuncSetAttribute((const void*)gemm8p<1>,
                      hipFuncAttributeMaxDynamicSharedMemorySize, G8_LDS);
  hipFuncSetAttribute((const void*)gemm8p<0>,
                      hipFuncAttributeMaxDynamicSharedMemorySize, G8_LDS);

  hipLaunchKernelGGL(pack_x, dim3((M_ROWS * 512 / 4) / 256), dim3(256), 0, stream,
                     Q, Xh, M_ROWS * 512 / 4);
  hipLaunchKernelGGL(pack_w, dim3((4 * 512 * 512) / 256), dim3(256), 0, stream,
                     Wq, Wk, Wv, Wo, Bqkv, Bo);
  hipLaunchKernelGGL(pack_bias, dim3(6), dim3(256), 0, stream, bq, bk, bv, bias_qkv);

  // QKV: M=8192, N=1536 -> 32x6 = 192 blocks
  gemm8p<1><<<dim3(192), dim3(512), G8_LDS, stream>>>(
      Xh, Bqkv, bias_qkv, (void*)QKV, M_ROWS, NQKV);

  hipLaunchKernelGGL(attn_win, dim3(B_SZ * N_HEADS * (L_SEQ / ATILE)), dim3(256),
                     ATTN_LDS, stream, QKV, AOh);

  // O: M=8192, N=512 -> 32x2 = 64 blocks
  gemm8p<0><<<dim3(64), dim3(512), G8_LDS, stream>>>(
      AOh, Bo, bo, (void*)out, M_ROWS, D_MODEL);
}

// Round 6
// 91.016 us; speedup vs baseline: 2.2180x; 1.1177x over previous
//
#include <hip/hip_runtime.h>
#include <hip/hip_bf16.h>

typedef unsigned short u16;
typedef short bf16x8 __attribute__((ext_vector_type(8)));
typedef u16 u16x8 __attribute__((ext_vector_type(8)));
typedef u16 u16x4 __attribute__((ext_vector_type(4)));
typedef float f32x4 __attribute__((ext_vector_type(4)));

#define D_MODEL 512
#define L_SEQ 2048
#define B_SZ 4
#define N_HEADS 8
#define D_K 64
#define M_ROWS 8192
#define NQKV 1536
#define WIN 10

__device__ inline u16 f2bf(float x) {
  __hip_bfloat16 h = __float2bfloat16(x);
  return *reinterpret_cast<u16*>(&h);
}
__device__ inline float bf2f(u16 u) {
  __hip_bfloat16 h;
  *reinterpret_cast<u16*>(&h) = u;
  return __bfloat162float(h);
}

// async global->LDS, 16B/lane; LDS dest = WAVE-UNIFORM base + lane*16 (HW)
__device__ inline void stage16(const void* gptr, void* ldsptr) {
  void* g = const_cast<void*>(gptr);
  __builtin_amdgcn_global_load_lds(
      (__attribute__((address_space(1))) void*)g,
      (__attribute__((address_space(3))) void*)ldsptr, 16, 0, 0);
}

template <int VMN>
__device__ inline void vmwait() {
  asm volatile("s_waitcnt vmcnt(%0)" ::"i"(VMN) : "memory");
}
#define BARX()                      \
  do {                              \
    asm volatile("" ::: "memory");  \
    __builtin_amdgcn_s_barrier();   \
    asm volatile("" ::: "memory");  \
  } while (0)

// =============== fused prep: pack_x | pack_w(transposed) | bias ===============
// blocks [0,4096): X->bf16. [4096,4352): W 64x64 LDS-transpose -> [N][1024] hi|lo.
// block 4352: bias concat.
__global__ __launch_bounds__(256) void prep(
    const float* __restrict__ X, const float* __restrict__ Wq,
    const float* __restrict__ Wk, const float* __restrict__ Wv,
    const float* __restrict__ Wo, const float* __restrict__ bq,
    const float* __restrict__ bk, const float* __restrict__ bv,
    u16* __restrict__ Xh, u16* __restrict__ Bqkv, u16* __restrict__ Bo,
    float* __restrict__ bias_qkv) {
  __shared__ float wlds[64 * 65];
  int blk = blockIdx.x, t = threadIdx.x;
  if (blk < 4096) {
    int i = blk * 256 + t;
    float4 x = ((const float4*)X)[i];
    u16x4 o;
    o[0] = f2bf(x.x); o[1] = f2bf(x.y); o[2] = f2bf(x.z); o[3] = f2bf(x.w);
    *(u16x4*)(Xh + i * 4) = o;
    return;
  }
  if (blk < 4352) {
    int tid = blk - 4096;           // 0..255
    int which = tid >> 6;           // W index
    int t64 = tid & 63;             // tile within W
    int k0 = (t64 >> 3) * 64, n0 = (t64 & 7) * 64;
    const float* W = which == 0 ? Wq : which == 1 ? Wk : which == 2 ? Wv : Wo;
    int c = t & 63, g = t >> 6;
#pragma unroll
    for (int rr = 0; rr < 16; ++rr) {
      int kl = g * 16 + rr;
      wlds[kl * 65 + c] = W[(size_t)(k0 + kl) * 512 + n0 + c];  // coalesced
    }
    __syncthreads();
    u16* dst = which < 3 ? Bqkv : Bo;
    int nbase = which < 3 ? which * 512 : 0;
#pragma unroll
    for (int rr = 0; rr < 16; ++rr) {
      int nl = g * 16 + rr;
      float v = wlds[c * 65 + nl];  // stride-65 col read: conflict-free
      u16 hi = f2bf(v);
      u16 lo = f2bf(v - bf2f(hi));
      size_t o = (size_t)(nbase + n0 + nl) * 1024 + k0 + c;
      dst[o] = hi;
      dst[o + 512] = lo;
    }
    return;
  }
  // bias
  for (int i = t; i < 1536; i += 256)
    bias_qkv[i] = i < 512 ? bq[i] : i < 1024 ? bk[i - 512] : bv[i - 1024];
}

// ================= QKV: 8-phase 256x256 GEMM, combined K=1024 =================
// m201-faithful phase order: {ds_read q; stage; vmcnt; barrier; MFMA}.
// Ledger: pair (kt,q) staged at phase (kt-1,q); confirmed for reading by the
// preceding phase's vmcnt(4)+barrier (q0 reads pairs 0,1; q1 pair 2; q2 pair 3).
// Waits: q0/q1/q3 -> vmcnt(4); q2 none (no barrier either). Tail: 2,0,-,-.
#define G8_LDS 131072

template <int PAIR>
__device__ inline void stage_pair(const char* Ab, const char* Bb, char* lds,
                                  long m0, long n0, int kt, int buf, int t, int w) {
  constexpr int off = PAIR == 0 ? 0 : PAIR == 3 ? 16384 : PAIR == 1 ? 32768 : 49152;
#pragma unroll
  for (int i = 0; i < 2; ++i) {
    int r = i * 64 + (t >> 3);
    int s = (t & 7) ^ (r & 7);  // inverse-swizzled source slot (rule 21)
    const char* src;
    if (PAIR == 0 || PAIR == 3)
      src = Ab + ((m0 + (PAIR == 3 ? 128 : 0) + r) * 512 + (long)(kt & 7) * 64) * 2 + s * 16;
    else
      src = Bb + ((n0 + (PAIR == 2 ? 128 : 0) + r) * 1024 + (long)kt * 64) * 2 + s * 16;
    stage16(src, lds + buf * 65536 + off + i * 8192 + w * 1024);
  }
}

__global__ __launch_bounds__(512, 1) void gemm_qkv8(
    const u16* __restrict__ A, const u16* __restrict__ Bc,
    const float* __restrict__ bias, u16* __restrict__ C) {
  extern __shared__ char lds[];
  const int t = threadIdx.x;
  const int w = t >> 6, lane = t & 63;
  const int fr = lane & 15, fo = lane >> 4;

  // XCD-bijective swizzle (192 % 8 == 0), m-tiles fastest
  int nwg = gridDim.x, bid = blockIdx.x;
  int swz = (bid & 7) * (nwg >> 3) + (bid >> 3);
  long m0 = (long)(swz & 31) << 8;
  long n0 = (long)(swz >> 5) << 8;

  const char* Ab = (const char*)A;
  const char* Bb = (const char*)Bc;

  auto LDA = [&](int buf, int mf, int ks) -> bf16x8 {
    int r = (w >> 2) * 64 + (mf & 3) * 16 + fr;
    return *(const bf16x8*)(lds + buf * 65536 + (mf >> 2) * 16384 + r * 128 +
                            (((ks * 4 + fo) ^ (fr & 7)) * 16));
  };
  auto LDB = [&](int buf, int nf, int ks) -> bf16x8 {
    int r = (w & 3) * 32 + (nf & 1) * 16 + fr;
    return *(const bf16x8*)(lds + buf * 65536 + 32768 + (nf >> 1) * 16384 + r * 128 +
                            (((ks * 4 + fo) ^ (fr & 7)) * 16));
  };

  f32x4 acc[8][4] = {};
  bf16x8 Af[4][2], Bf[4][2];

#define MFMA_Q(MBASE, NLO)                                               \
  __builtin_amdgcn_s_setprio(1);                                         \
  _Pragma("unroll") for (int mf = 0; mf < 4; ++mf)                       \
      _Pragma("unroll") for (int nf = NLO; nf < NLO + 2; ++nf) {         \
    acc[MBASE + mf][nf] = __builtin_amdgcn_mfma_f32_16x16x32_bf16(       \
        Af[mf][0], Bf[nf][0], acc[MBASE + mf][nf], 0, 0, 0);             \
    acc[MBASE + mf][nf] = __builtin_amdgcn_mfma_f32_16x16x32_bf16(       \
        Af[mf][1], Bf[nf][1], acc[MBASE + mf][nf], 0, 0, 0);             \
  }                                                                      \
  __builtin_amdgcn_s_setprio(0);

  // prologue: stage tile 0, confirm pairs 0,1
  stage_pair<0>(Ab, Bb, lds, m0, n0, 0, 0, t, w);
  stage_pair<1>(Ab, Bb, lds, m0, n0, 0, 0, t, w);
  stage_pair<2>(Ab, Bb, lds, m0, n0, 0, 0, t, w);
  stage_pair<3>(Ab, Bb, lds, m0, n0, 0, 0, t, w);
  vmwait<4>();
  BARX();

  for (int kt = 0; kt < 15; ++kt) {
    const int cur = kt & 1, nxt = cur ^ 1, kn = kt + 1;
    // q0: A0 x B0
#pragma unroll
    for (int mf = 0; mf < 4; ++mf) {
      Af[mf][0] = LDA(cur, mf, 0);
      Af[mf][1] = LDA(cur, mf, 1);
    }
#pragma unroll
    for (int nf = 0; nf < 2; ++nf) {
      Bf[nf][0] = LDB(cur, nf, 0);
      Bf[nf][1] = LDB(cur, nf, 1);
    }
    stage_pair<0>(Ab, Bb, lds, m0, n0, kn, nxt, t, w);
    vmwait<4>();
    BARX();
    MFMA_Q(0, 0);
    // q1: A0 x B1
#pragma unroll
    for (int nf = 2; nf < 4; ++nf) {
      Bf[nf][0] = LDB(cur, nf, 0);
      Bf[nf][1] = LDB(cur, nf, 1);
    }
    stage_pair<1>(Ab, Bb, lds, m0, n0, kn, nxt, t, w);
    vmwait<4>();
    BARX();
    MFMA_Q(0, 2);
    // q2: A1 x B1 (no wait/barrier; pair 3 confirmed at q1)
#pragma unroll
    for (int mf = 0; mf < 4; ++mf) {
      Af[mf][0] = LDA(cur, mf + 4, 0);
      Af[mf][1] = LDA(cur, mf + 4, 1);
    }
    stage_pair<2>(Ab, Bb, lds, m0, n0, kn, nxt, t, w);
    MFMA_Q(4, 2);
    // q3: A1 x B0 (regs held)
    stage_pair<3>(Ab, Bb, lds, m0, n0, kn, nxt, t, w);
    vmwait<4>();
    BARX();
    MFMA_Q(4, 0);
  }

  // tail tile 15 (buf 1), no staging
  {
#pragma unroll
    for (int mf = 0; mf < 4; ++mf) {
      Af[mf][0] = LDA(1, mf, 0);
      Af[mf][1] = LDA(1, mf, 1);
    }
#pragma unroll
    for (int nf = 0; nf < 2; ++nf) {
      Bf[nf][0] = LDB(1, nf, 0);
      Bf[nf][1] = LDB(1, nf, 1);
    }
    vmwait<2>();
    BARX();
    MFMA_Q(0, 0);
#pragma unroll
    for (int nf = 2; nf < 4; ++nf) {
      Bf[nf][0] = LDB(1, nf, 0);
      Bf[nf][1] = LDB(1, nf, 1);
    }
    vmwait<0>();
    BARX();
    MFMA_Q(0, 2);
#pragma unroll
    for (int mf = 0; mf < 4; ++mf) {
      Af[mf][0] = LDA(1, mf + 4, 0);
      Af[mf][1] = LDA(1, mf + 4, 1);
    }
    MFMA_Q(4, 2);
    MFMA_Q(4, 0);
  }
#undef MFMA_Q

  // epilogue: C/D frag col = lane&15, row = 4*(lane>>4)+q
#pragma unroll
  for (int nf = 0; nf < 4; ++nf) {
    long col = n0 + (nf >> 1) * 128 + (w & 3) * 32 + (nf & 1) * 16 + fr;
    float bn = bias[col];
#pragma unroll
    for (int mf = 0; mf < 8; ++mf) {
      long row = m0 + (mf >> 2) * 128 + (w >> 2) * 64 + (mf & 3) * 16 + fo * 4;
#pragma unroll
      for (int q = 0; q < 4; ++q)
        C[(size_t)(row + q) * NQKV + col] = f2bf(acc[mf][nf][q] + bn);
    }
  }
}

// ========== O-proj: m97-structure 128x128 2-phase, combined K=1024 ==========
__global__ __launch_bounds__(256) void gemm_o(const u16* __restrict__ A,
                                              const u16* __restrict__ Bc,
                                              const float* __restrict__ bias,
                                              float* __restrict__ C) {
  __shared__ u16 sA[128 * 32], sB[128 * 32];
  int t = threadIdx.x, w = t >> 6, lane = t & 63;
  long m0 = (long)blockIdx.y * 128, n0 = (long)blockIdx.x * 128;
  int wm = (w >> 1) * 64, wn = (w & 1) * 64;
  int fr = lane & 15, fo = lane >> 4;
  int rl = lane >> 2, cb = (lane & 3) * 16;
  const char* Ab = (const char*)A;
  const char* Bb = (const char*)Bc;

  f32x4 acc[4][4] = {};

  for (int kt = 0; kt < 32; ++kt) {
#pragma unroll
    for (int c = 0; c < 2; ++c) {
      int ch = w * 2 + c;
      int row = ch * 16 + rl;
      stage16(Ab + ((m0 + row) * 512 + (long)(kt & 15) * 32) * 2 + cb,
              (char*)sA + ch * 1024);
      stage16(Bb + ((n0 + row) * 1024 + (long)kt * 32) * 2 + cb,
              (char*)sB + ch * 1024);
    }
    __syncthreads();  // drains vmcnt(0)

    bf16x8 af[4], bf[4];
#pragma unroll
    for (int m = 0; m < 4; ++m) af[m] = *(const bf16x8*)&sA[(wm + m * 16 + fr) * 32 + fo * 8];
#pragma unroll
    for (int n = 0; n < 4; ++n) bf[n] = *(const bf16x8*)&sB[(wn + n * 16 + fr) * 32 + fo * 8];
#pragma unroll
    for (int m = 0; m < 4; ++m)
#pragma unroll
      for (int n = 0; n < 4; ++n)
        acc[m][n] = __builtin_amdgcn_mfma_f32_16x16x32_bf16(af[m], bf[n], acc[m][n], 0, 0, 0);
    __syncthreads();
  }

  int rbase = m0 + wm + fo * 4, cbase = n0 + wn + fr;
#pragma unroll
  for (int n = 0; n < 4; ++n) {
    int col = cbase + n * 16;
    float bn = bias[col];
#pragma unroll
    for (int m = 0; m < 4; ++m) {
      int row = rbase + m * 16;
#pragma unroll
      for (int q = 0; q < 4; ++q)
        C[(size_t)(row + q) * 512 + col] = acc[m][n][q] + bn;
    }
  }
}

// ---------------- windowed attention: diagonal form, bf16 QKV in ----------------
#define ATILE 128
#define KROWS (ATILE + 2 * WIN)   /* 148 */
#define LQ 133
#define LK 149
#define ATTN_LDS ((64 * LQ + 64 * LK) * 4)  /* 72192 B */

__global__ __launch_bounds__(256) void attn_win(const u16* __restrict__ QKV,
                                                u16* __restrict__ AOh) {
  extern __shared__ float flds[];
  float* sQ = flds;            // [64][LQ]
  float* sK = flds + 64 * LQ;  // [64][LK], reused for V

  int t = threadIdx.x;
  int blk = blockIdx.x;
  int tile = blk & 15;
  int h = (blk >> 4) & 7;
  int b = blk >> 7;
  int l0 = tile * ATILE;
  const u16* base = QKV + (size_t)b * L_SEQ * NQKV + h * D_K;

  int kq = t & 7;
  int ir = t >> 3;

#pragma unroll
  for (int p = 0; p < 4; ++p) {
    int i = ir + p * 32;
    u16x8 g = *(const u16x8*)(base + (size_t)(l0 + i) * NQKV + kq * 8);
#pragma unroll
    for (int e = 0; e < 8; ++e)
      sQ[(8 * kq + e) * LQ + i] = bf2f(g[e]);
  }
#pragma unroll
  for (int p = 0; p < 5; ++p) {
    int i = ir + p * 32;
    if (i < KROWS) {
      int l = min(max(l0 - WIN + i, 0), L_SEQ - 1);
      u16x8 g = *(const u16x8*)(base + (size_t)l * NQKV + 512 + kq * 8);
#pragma unroll
      for (int e = 0; e < 8; ++e)
        sK[(8 * kq + e) * LK + i] = bf2f(g[e]);
    }
  }
  __syncthreads();

  int w = t >> 6, lane = t & 63;
  int qloc = w * 32 + (lane & 31);
  int dbase = (lane >> 5) * 32;
  int myl = l0 + qloc;

  float s[21];
#pragma unroll
  for (int o = 0; o < 21; ++o) s[o] = 0.f;

  for (int d = 0; d < 32; ++d) {
    float qd = sQ[(dbase + d) * LQ + qloc];
    const float* kr = &sK[(dbase + d) * LK + qloc];
#pragma unroll
    for (int o = 0; o < 21; ++o)
      s[o] += qd * kr[o];
  }
#pragma unroll
  for (int o = 0; o < 21; ++o) s[o] += __shfl_xor(s[o], 32);

  float m = -3.0e38f;
#pragma unroll
  for (int o = 0; o < 21; ++o) {
    int j = myl - WIN + o;
    float sv = fminf(fmaxf(s[o] * 0.125f, -10000.f), 10000.f);
    s[o] = (j >= 0 && j < L_SEQ) ? sv : -3.0e38f;
    m = fmaxf(m, s[o]);
  }
  float lsum = 0.f;
#pragma unroll
  for (int o = 0; o < 21; ++o) {
    float e = (s[o] > -1.0e37f) ? __expf(s[o] - m) : 0.f;
    s[o] = e;
    lsum += e;
  }
  float inv = 1.f / lsum;

  __syncthreads();
#pragma unroll
  for (int p = 0; p < 5; ++p) {
    int i = ir + p * 32;
    if (i < KROWS) {
      int l = min(max(l0 - WIN + i, 0), L_SEQ - 1);
      u16x8 g = *(const u16x8*)(base + (size_t)l * NQKV + 1024 + kq * 8);
#pragma unroll
      for (int e = 0; e < 8; ++e)
        sK[(8 * kq + e) * LK + i] = bf2f(g[e]);
    }
  }
  __syncthreads();

  size_t orow = ((size_t)(b * L_SEQ + myl)) * D_MODEL + h * D_K + dbase;
#pragma unroll
  for (int g8 = 0; g8 < 4; ++g8) {
    u16x8 hi8;
#pragma unroll
    for (int dd = 0; dd < 8; ++dd) {
      int d = dbase + g8 * 8 + dd;
      const float* vr = &sK[d * LK + qloc];
      float a = 0.f;
#pragma unroll
      for (int o = 0; o < 21; ++o)
        a += s[o] * vr[o];
      hi8[dd] = f2bf(a * inv);
    }
    *(u16x8*)(AOh + orow + g8 * 8) = hi8;
  }
}

extern "C" void kernel_launch(void* const* d_in, const int* in_sizes, int n_in,
                              void* d_out, int out_size, void* d_ws, size_t ws_size,
                              hipStream_t stream) {
  const float* Q  = (const float*)d_in[0];
  const float* Wq = (const float*)d_in[1];
  const float* bq = (const float*)d_in[2];
  const float* Wk = (const float*)d_in[3];
  const float* bk = (const float*)d_in[4];
  const float* Wv = (const float*)d_in[5];
  const float* bv = (const float*)d_in[6];
  const float* Wo = (const float*)d_in[7];
  const float* bo = (const float*)d_in[8];
  float* out = (float*)d_out;

  char* p = (char*)d_ws;
  u16* Xh = (u16*)p;        p += (size_t)M_ROWS * 512 * 2;
  u16* Bqkv = (u16*)p;      p += (size_t)1536 * 1024 * 2;
  u16* Bo = (u16*)p;        p += (size_t)512 * 1024 * 2;
  float* bias_qkv = (float*)p; p += 1536 * 4;
  u16* QKV = (u16*)p;       p += (size_t)M_ROWS * 1536 * 2;
  u16* AOh = (u16*)p;       p += (size_t)M_ROWS * 512 * 2;

  hipFuncSetAttribute((const void*)attn_win,
                      hipFuncAttributeMaxDynamicSharedMemorySize, ATTN_LDS);
  hipFuncSetAttribute((const void*)gemm_qkv8,
                      hipFuncAttributeMaxDynamicSharedMemorySize, G8_LDS);

  hipLaunchKernelGGL(prep, dim3(4353), dim3(256), 0, stream,
                     Q, Wq, Wk, Wv, Wo, bq, bk, bv, Xh, Bqkv, Bo, bias_qkv);

  // QKV: 32 m-tiles x 6 n-tiles = 192 blocks
  gemm_qkv8<<<dim3(192), dim3(512), G8_LDS, stream>>>(Xh, Bqkv, bias_qkv, QKV);

  hipLaunchKernelGGL(attn_win, dim3(B_SZ * N_HEADS * (L_SEQ / ATILE)), dim3(256),
                     ATTN_LDS, stream, QKV, AOh);

  // O: 4 n-tiles x 64 m-tiles = 256 blocks (full CU fill)
  gemm_o<<<dim3(4, 64), dim3(256), 0, stream>>>(AOh, Bo, bo, out);
}

// Round 7
// 74.633 us; speedup vs baseline: 2.7050x; 1.2195x over previous
//
#include <hip/hip_runtime.h>
#include <hip/hip_bf16.h>

typedef unsigned short u16;
typedef short bf16x8 __attribute__((ext_vector_type(8)));
typedef u16 u16x8 __attribute__((ext_vector_type(8)));
typedef u16 u16x4 __attribute__((ext_vector_type(4)));
typedef float f32x4 __attribute__((ext_vector_type(4)));

#define D_MODEL 512
#define L_SEQ 2048
#define B_SZ 4
#define N_HEADS 8
#define D_K 64
#define M_ROWS 8192
#define NQKV 1536
#define WIN 10

__device__ inline u16 f2bf(float x) {
  __hip_bfloat16 h = __float2bfloat16(x);
  return *reinterpret_cast<u16*>(&h);
}
__device__ inline float bf2f(u16 u) {
  __hip_bfloat16 h;
  *reinterpret_cast<u16*>(&h) = u;
  return __bfloat162float(h);
}

// async global->LDS, 16B/lane; LDS dest = WAVE-UNIFORM base + lane*16 (HW)
__device__ inline void stage16(const void* gptr, void* ldsptr) {
  void* g = const_cast<void*>(gptr);
  __builtin_amdgcn_global_load_lds(
      (__attribute__((address_space(1))) void*)g,
      (__attribute__((address_space(3))) void*)ldsptr, 16, 0, 0);
}

// =============== fused prep: pack_x | pack_w(transposed, bf16) | bias ===============
__global__ __launch_bounds__(256) void prep(
    const float* __restrict__ X, const float* __restrict__ Wq,
    const float* __restrict__ Wk, const float* __restrict__ Wv,
    const float* __restrict__ Wo, const float* __restrict__ bq,
    const float* __restrict__ bk, const float* __restrict__ bv,
    u16* __restrict__ Xh, u16* __restrict__ Bqkv, u16* __restrict__ Bo,
    float* __restrict__ bias_qkv) {
  __shared__ float wlds[64 * 65];
  int blk = blockIdx.x, t = threadIdx.x;
  if (blk < 4096) {
    int i = blk * 256 + t;
    float4 x = ((const float4*)X)[i];
    u16x4 o;
    o[0] = f2bf(x.x); o[1] = f2bf(x.y); o[2] = f2bf(x.z); o[3] = f2bf(x.w);
    *(u16x4*)(Xh + i * 4) = o;
    return;
  }
  if (blk < 4352) {
    int tid = blk - 4096;           // 0..255
    int which = tid >> 6;           // W index
    int t64 = tid & 63;             // 64x64 tile within W
    int k0 = (t64 >> 3) * 64, n0 = (t64 & 7) * 64;
    const float* W = which == 0 ? Wq : which == 1 ? Wk : which == 2 ? Wv : Wo;
    int c = t & 63, g = t >> 6;
#pragma unroll
    for (int rr = 0; rr < 16; ++rr) {
      int kl = g * 16 + rr;
      wlds[kl * 65 + c] = W[(size_t)(k0 + kl) * 512 + n0 + c];  // coalesced
    }
    __syncthreads();
    u16* dst = which < 3 ? Bqkv : Bo;
    int nbase = which < 3 ? which * 512 : 0;
#pragma unroll
    for (int rr = 0; rr < 16; ++rr) {
      int nl = g * 16 + rr;
      float v = wlds[c * 65 + nl];  // stride-65 col read: conflict-free
      dst[(size_t)(nbase + n0 + nl) * 512 + k0 + c] = f2bf(v);
    }
    return;
  }
  for (int i = t; i < 1536; i += 256)
    bias_qkv[i] = i < 512 ? bq[i] : i < 1024 ? bk[i - 512] : bv[i - 1024];
}

// ========== QKV GEMM: 128x128 tile, BK=32, K=512, 2-phase double-buffer ==========
// T3-minimum recipe: stage(next buf) issued BEFORE ds_read+MFMA of current buf;
// __syncthreads() at iter end performs the vmcnt(0)+lgkmcnt(0) drain + barrier.
__global__ __launch_bounds__(256) void gemm_qkv(
    const u16* __restrict__ A, const u16* __restrict__ B,
    const float* __restrict__ bias, u16* __restrict__ C) {
  __shared__ u16 sA[2][128 * 32], sB[2][128 * 32];
  int t = threadIdx.x, w = t >> 6, lane = t & 63;
  long m0 = (long)blockIdx.y * 128, n0 = (long)blockIdx.x * 128;
  int wm = (w >> 1) * 64, wn = (w & 1) * 64;
  int fr = lane & 15, fo = lane >> 4;
  int rl = lane >> 2, cb = (lane & 3) * 16;
  const char* Ab = (const char*)A;
  const char* Bb = (const char*)B;

  f32x4 acc[4][4] = {};

  // stage: tile rows in 1KB chunks (16 rows x 64B); chunks {w, w+4} per wave
#define STAGE_QKV(buf, kt)                                                  \
  do {                                                                      \
    int c0 = w, c1 = w + 4;                                                 \
    int r0 = c0 * 16 + rl, r1 = c1 * 16 + rl;                               \
    stage16(Ab + ((m0 + r0) * 512 + (long)(kt) * 32) * 2 + cb,              \
            (char*)sA[buf] + c0 * 1024);                                    \
    stage16(Bb + ((n0 + r0) * 512 + (long)(kt) * 32) * 2 + cb,              \
            (char*)sB[buf] + c0 * 1024);                                    \
    stage16(Ab + ((m0 + r1) * 512 + (long)(kt) * 32) * 2 + cb,              \
            (char*)sA[buf] + c1 * 1024);                                    \
    stage16(Bb + ((n0 + r1) * 512 + (long)(kt) * 32) * 2 + cb,              \
            (char*)sB[buf] + c1 * 1024);                                    \
  } while (0)

  STAGE_QKV(0, 0);
  __syncthreads();

  for (int kt = 0; kt < 16; ++kt) {
    int cur = kt & 1;
    if (kt < 15) STAGE_QKV(cur ^ 1, kt + 1);
    bf16x8 af[4], bf[4];
#pragma unroll
    for (int m = 0; m < 4; ++m)
      af[m] = *(const bf16x8*)&sA[cur][(wm + m * 16 + fr) * 32 + fo * 8];
#pragma unroll
    for (int n = 0; n < 4; ++n)
      bf[n] = *(const bf16x8*)&sB[cur][(wn + n * 16 + fr) * 32 + fo * 8];
#pragma unroll
    for (int m = 0; m < 4; ++m)
#pragma unroll
      for (int n = 0; n < 4; ++n)
        acc[m][n] = __builtin_amdgcn_mfma_f32_16x16x32_bf16(af[m], bf[n], acc[m][n], 0, 0, 0);
    __syncthreads();  // drains vmcnt(0): next buf staged; protects cur for reuse
  }
#undef STAGE_QKV

  int rbase = m0 + wm + fo * 4, cbase = n0 + wn + fr;
#pragma unroll
  for (int n = 0; n < 4; ++n) {
    int col = cbase + n * 16;
    float bn = bias[col];
#pragma unroll
    for (int m = 0; m < 4; ++m) {
      int row = rbase + m * 16;
#pragma unroll
      for (int q = 0; q < 4; ++q)
        C[(size_t)(row + q) * NQKV + col] = f2bf(acc[m][n][q] + bn);
    }
  }
}

// ========== O GEMM: 64x128 tile (512 blocks = 2/CU), BK=32, 2-phase dbuf ==========
__global__ __launch_bounds__(256) void gemm_o(
    const u16* __restrict__ A, const u16* __restrict__ B,
    const float* __restrict__ bias, float* __restrict__ C) {
  __shared__ u16 sA[2][64 * 32], sB[2][128 * 32];
  int t = threadIdx.x, w = t >> 6, lane = t & 63;
  long m0 = (long)blockIdx.y * 64, n0 = (long)blockIdx.x * 128;
  int wn = w * 32;
  int fr = lane & 15, fo = lane >> 4;
  int rl = lane >> 2, cb = (lane & 3) * 16;
  const char* Ab = (const char*)A;
  const char* Bb = (const char*)B;

  f32x4 acc[4][2] = {};

#define STAGE_O(buf, kt)                                                    \
  do {                                                                      \
    int ra = w * 16 + rl;                                                   \
    stage16(Ab + ((m0 + ra) * 512 + (long)(kt) * 32) * 2 + cb,              \
            (char*)sA[buf] + w * 1024);                                     \
    int c0 = w, c1 = w + 4;                                                 \
    int r0 = c0 * 16 + rl, r1 = c1 * 16 + rl;                               \
    stage16(Bb + ((n0 + r0) * 512 + (long)(kt) * 32) * 2 + cb,              \
            (char*)sB[buf] + c0 * 1024);                                    \
    stage16(Bb + ((n0 + r1) * 512 + (long)(kt) * 32) * 2 + cb,              \
            (char*)sB[buf] + c1 * 1024);                                    \
  } while (0)

  STAGE_O(0, 0);
  __syncthreads();

  for (int kt = 0; kt < 16; ++kt) {
    int cur = kt & 1;
    if (kt < 15) STAGE_O(cur ^ 1, kt + 1);
    bf16x8 af[4], bf[2];
#pragma unroll
    for (int m = 0; m < 4; ++m)
      af[m] = *(const bf16x8*)&sA[cur][(m * 16 + fr) * 32 + fo * 8];
#pragma unroll
    for (int n = 0; n < 2; ++n)
      bf[n] = *(const bf16x8*)&sB[cur][(wn + n * 16 + fr) * 32 + fo * 8];
#pragma unroll
    for (int m = 0; m < 4; ++m)
#pragma unroll
      for (int n = 0; n < 2; ++n)
        acc[m][n] = __builtin_amdgcn_mfma_f32_16x16x32_bf16(af[m], bf[n], acc[m][n], 0, 0, 0);
    __syncthreads();
  }
#undef STAGE_O

  int rbase = m0 + fo * 4, cbase = n0 + wn + fr;
#pragma unroll
  for (int n = 0; n < 2; ++n) {
    int col = cbase + n * 16;
    float bn = bias[col];
#pragma unroll
    for (int m = 0; m < 4; ++m) {
      int row = rbase + m * 16;
#pragma unroll
      for (int q = 0; q < 4; ++q)
        C[(size_t)(row + q) * 512 + col] = acc[m][n][q] + bn;
    }
  }
}

// ---------------- windowed attention: diagonal form, bf16 QKV in ----------------
#define ATILE 128
#define KROWS (ATILE + 2 * WIN)   /* 148 */
#define LQ 133
#define LK 149
#define ATTN_LDS ((64 * LQ + 64 * LK) * 4)  /* 72192 B */

__global__ __launch_bounds__(256) void attn_win(const u16* __restrict__ QKV,
                                                u16* __restrict__ AOh) {
  extern __shared__ float flds[];
  float* sQ = flds;            // [64][LQ]
  float* sK = flds + 64 * LQ;  // [64][LK], reused for V

  int t = threadIdx.x;
  int blk = blockIdx.x;
  int tile = blk & 15;
  int h = (blk >> 4) & 7;
  int b = blk >> 7;
  int l0 = tile * ATILE;
  const u16* base = QKV + (size_t)b * L_SEQ * NQKV + h * D_K;

  int kq = t & 7;
  int ir = t >> 3;

#pragma unroll
  for (int p = 0; p < 4; ++p) {
    int i = ir + p * 32;
    u16x8 g = *(const u16x8*)(base + (size_t)(l0 + i) * NQKV + kq * 8);
#pragma unroll
    for (int e = 0; e < 8; ++e)
      sQ[(8 * kq + e) * LQ + i] = bf2f(g[e]);
  }
#pragma unroll
  for (int p = 0; p < 5; ++p) {
    int i = ir + p * 32;
    if (i < KROWS) {
      int l = min(max(l0 - WIN + i, 0), L_SEQ - 1);
      u16x8 g = *(const u16x8*)(base + (size_t)l * NQKV + 512 + kq * 8);
#pragma unroll
      for (int e = 0; e < 8; ++e)
        sK[(8 * kq + e) * LK + i] = bf2f(g[e]);
    }
  }
  __syncthreads();

  int w = t >> 6, lane = t & 63;
  int qloc = w * 32 + (lane & 31);
  int dbase = (lane >> 5) * 32;
  int myl = l0 + qloc;

  float s[21];
#pragma unroll
  for (int o = 0; o < 21; ++o) s[o] = 0.f;

  for (int d = 0; d < 32; ++d) {
    float qd = sQ[(dbase + d) * LQ + qloc];
    const float* kr = &sK[(dbase + d) * LK + qloc];
#pragma unroll
    for (int o = 0; o < 21; ++o)
      s[o] += qd * kr[o];
  }
#pragma unroll
  for (int o = 0; o < 21; ++o) s[o] += __shfl_xor(s[o], 32);

  float m = -3.0e38f;
#pragma unroll
  for (int o = 0; o < 21; ++o) {
    int j = myl - WIN + o;
    float sv = fminf(fmaxf(s[o] * 0.125f, -10000.f), 10000.f);
    s[o] = (j >= 0 && j < L_SEQ) ? sv : -3.0e38f;
    m = fmaxf(m, s[o]);
  }
  float lsum = 0.f;
#pragma unroll
  for (int o = 0; o < 21; ++o) {
    float e = (s[o] > -1.0e37f) ? __expf(s[o] - m) : 0.f;
    s[o] = e;
    lsum += e;
  }
  float inv = 1.f / lsum;

  __syncthreads();
#pragma unroll
  for (int p = 0; p < 5; ++p) {
    int i = ir + p * 32;
    if (i < KROWS) {
      int l = min(max(l0 - WIN + i, 0), L_SEQ - 1);
      u16x8 g = *(const u16x8*)(base + (size_t)l * NQKV + 1024 + kq * 8);
#pragma unroll
      for (int e = 0; e < 8; ++e)
        sK[(8 * kq + e) * LK + i] = bf2f(g[e]);
    }
  }
  __syncthreads();

  size_t orow = ((size_t)(b * L_SEQ + myl)) * D_MODEL + h * D_K + dbase;
#pragma unroll
  for (int g8 = 0; g8 < 4; ++g8) {
    u16x8 hi8;
#pragma unroll
    for (int dd = 0; dd < 8; ++dd) {
      int d = dbase + g8 * 8 + dd;
      const float* vr = &sK[d * LK + qloc];
      float a = 0.f;
#pragma unroll
      for (int o = 0; o < 21; ++o)
        a += s[o] * vr[o];
      hi8[dd] = f2bf(a * inv);
    }
    *(u16x8*)(AOh + orow + g8 * 8) = hi8;
  }
}

extern "C" void kernel_launch(void* const* d_in, const int* in_sizes, int n_in,
                              void* d_out, int out_size, void* d_ws, size_t ws_size,
                              hipStream_t stream) {
  const float* Q  = (const float*)d_in[0];
  const float* Wq = (const float*)d_in[1];
  const float* bq = (const float*)d_in[2];
  const float* Wk = (const float*)d_in[3];
  const float* bk = (const float*)d_in[4];
  const float* Wv = (const float*)d_in[5];
  const float* bv = (const float*)d_in[6];
  const float* Wo = (const float*)d_in[7];
  const float* bo = (const float*)d_in[8];
  float* out = (float*)d_out;

  char* p = (char*)d_ws;
  u16* Xh = (u16*)p;        p += (size_t)M_ROWS * 512 * 2;
  u16* Bqkv = (u16*)p;      p += (size_t)1536 * 512 * 2;
  u16* Bo = (u16*)p;        p += (size_t)512 * 512 * 2;
  float* bias_qkv = (float*)p; p += 1536 * 4;
  u16* QKV = (u16*)p;       p += (size_t)M_ROWS * 1536 * 2;
  u16* AOh = (u16*)p;       p += (size_t)M_ROWS * 512 * 2;

  hipFuncSetAttribute((const void*)attn_win,
                      hipFuncAttributeMaxDynamicSharedMemorySize, ATTN_LDS);

  hipLaunchKernelGGL(prep, dim3(4353), dim3(256), 0, stream,
                     Q, Wq, Wk, Wv, Wo, bq, bk, bv, Xh, Bqkv, Bo, bias_qkv);

  // QKV: 12 n-tiles x 64 m-tiles = 768 blocks (3/CU)
  gemm_qkv<<<dim3(12, 64), dim3(256), 0, stream>>>(Xh, Bqkv, bias_qkv, QKV);

  hipLaunchKernelGGL(attn_win, dim3(B_SZ * N_HEADS * (L_SEQ / ATILE)), dim3(256),
                     ATTN_LDS, stream, QKV, AOh);

  // O: 4 n-tiles x 128 m-tiles = 512 blocks (2/CU)
  gemm_o<<<dim3(4, 128), dim3(256), 0, stream>>>(AOh, Bo, bo, out);
}

// Round 9
// 59.508 us; speedup vs baseline: 3.3925x; 1.2542x over previous
//
#include <hip/hip_runtime.h>
#include <hip/hip_bf16.h>

typedef unsigned short u16;
typedef short bf16x8 __attribute__((ext_vector_type(8)));
typedef u16 u16x8 __attribute__((ext_vector_type(8)));
typedef u16 u16x4 __attribute__((ext_vector_type(4)));
typedef float f32x4 __attribute__((ext_vector_type(4)));

#define D_MODEL 512
#define L_SEQ 2048
#define B_SZ 4
#define N_HEADS 8
#define D_K 64
#define M_ROWS 8192
#define NQKV 1536
#define WIN 10

__device__ inline u16 f2bf(float x) {
  __hip_bfloat16 h = __float2bfloat16(x);
  return *reinterpret_cast<u16*>(&h);
}
__device__ inline float bf2f(u16 u) {
  __hip_bfloat16 h;
  *reinterpret_cast<u16*>(&h) = u;
  return __bfloat162float(h);
}

// async global->LDS, 16B/lane; LDS dest = WAVE-UNIFORM base + lane*16 (HW)
__device__ inline void stage16(const void* gptr, void* ldsptr) {
  void* g = const_cast<void*>(gptr);
  __builtin_amdgcn_global_load_lds(
      (__attribute__((address_space(1))) void*)g,
      (__attribute__((address_space(3))) void*)ldsptr, 16, 0, 0);
}

// =============== fused prep: pack_x | pack_w(transposed, bf16) | bias ===============
__global__ __launch_bounds__(256) void prep(
    const float* __restrict__ X, const float* __restrict__ Wq,
    const float* __restrict__ Wk, const float* __restrict__ Wv,
    const float* __restrict__ Wo, const float* __restrict__ bq,
    const float* __restrict__ bk, const float* __restrict__ bv,
    u16* __restrict__ Xh, u16* __restrict__ Bqkv, u16* __restrict__ Bo,
    float* __restrict__ bias_qkv) {
  __shared__ float wlds[64 * 65];
  int blk = blockIdx.x, t = threadIdx.x;
  if (blk < 4096) {
    int i = blk * 256 + t;
    float4 x = ((const float4*)X)[i];
    u16x4 o;
    o[0] = f2bf(x.x); o[1] = f2bf(x.y); o[2] = f2bf(x.z); o[3] = f2bf(x.w);
    *(u16x4*)(Xh + i * 4) = o;
    return;
  }
  if (blk < 4352) {
    int tid = blk - 4096;           // 0..255
    int which = tid >> 6;           // W index
    int t64 = tid & 63;             // 64x64 tile within W
    int k0 = (t64 >> 3) * 64, n0 = (t64 & 7) * 64;
    const float* W = which == 0 ? Wq : which == 1 ? Wk : which == 2 ? Wv : Wo;
    int c = t & 63, g = t >> 6;
#pragma unroll
    for (int rr = 0; rr < 16; ++rr) {
      int kl = g * 16 + rr;
      wlds[kl * 65 + c] = W[(size_t)(k0 + kl) * 512 + n0 + c];  // coalesced
    }
    __syncthreads();
    u16* dst = which < 3 ? Bqkv : Bo;
    int nbase = which < 3 ? which * 512 : 0;
#pragma unroll
    for (int rr = 0; rr < 16; ++rr) {
      int nl = g * 16 + rr;
      float v = wlds[c * 65 + nl];  // stride-65 col read: conflict-free
      dst[(size_t)(nbase + n0 + nl) * 512 + k0 + c] = f2bf(v);
    }
    return;
  }
  for (int i = t; i < 1536; i += 256)
    bias_qkv[i] = i < 512 ? bq[i] : i < 1024 ? bk[i - 512] : bv[i - 1024];
}

// ========== QKV GEMM: 128x128 tile, BK=32, K=512, 2-phase double-buffer ==========
__global__ __launch_bounds__(256) void gemm_qkv(
    const u16* __restrict__ A, const u16* __restrict__ B,
    const float* __restrict__ bias, u16* __restrict__ C) {
  __shared__ u16 sA[2][128 * 32], sB[2][128 * 32];
  int t = threadIdx.x, w = t >> 6, lane = t & 63;
  // XCD-bijective swizzle: 768 blocks (12 n x 64 m)
  int bid = blockIdx.y * 12 + blockIdx.x;
  int swz = (bid & 7) * 96 + (bid >> 3);
  long m0 = (long)(swz / 12) * 128, n0 = (long)(swz % 12) * 128;
  int wm = (w >> 1) * 64, wn = (w & 1) * 64;
  int fr = lane & 15, fo = lane >> 4;
  int rl = lane >> 2, cb = (lane & 3) * 16;
  const char* Ab = (const char*)A;
  const char* Bb = (const char*)B;

  f32x4 acc[4][4] = {};

#define STAGE_QKV(buf, kt)                                                  \
  do {                                                                      \
    int c0 = w, c1 = w + 4;                                                 \
    int r0 = c0 * 16 + rl, r1 = c1 * 16 + rl;                               \
    stage16(Ab + ((m0 + r0) * 512 + (long)(kt) * 32) * 2 + cb,              \
            (char*)sA[buf] + c0 * 1024);                                    \
    stage16(Bb + ((n0 + r0) * 512 + (long)(kt) * 32) * 2 + cb,              \
            (char*)sB[buf] + c0 * 1024);                                    \
    stage16(Ab + ((m0 + r1) * 512 + (long)(kt) * 32) * 2 + cb,              \
            (char*)sA[buf] + c1 * 1024);                                    \
    stage16(Bb + ((n0 + r1) * 512 + (long)(kt) * 32) * 2 + cb,              \
            (char*)sB[buf] + c1 * 1024);                                    \
  } while (0)

  STAGE_QKV(0, 0);
  __syncthreads();

  for (int kt = 0; kt < 16; ++kt) {
    int cur = kt & 1;
    if (kt < 15) STAGE_QKV(cur ^ 1, kt + 1);
    bf16x8 af[4], bf[4];
#pragma unroll
    for (int m = 0; m < 4; ++m)
      af[m] = *(const bf16x8*)&sA[cur][(wm + m * 16 + fr) * 32 + fo * 8];
#pragma unroll
    for (int n = 0; n < 4; ++n)
      bf[n] = *(const bf16x8*)&sB[cur][(wn + n * 16 + fr) * 32 + fo * 8];
#pragma unroll
    for (int m = 0; m < 4; ++m)
#pragma unroll
      for (int n = 0; n < 4; ++n)
        acc[m][n] = __builtin_amdgcn_mfma_f32_16x16x32_bf16(af[m], bf[n], acc[m][n], 0, 0, 0);
    __syncthreads();
  }
#undef STAGE_QKV

  int rbase = m0 + wm + fo * 4, cbase = n0 + wn + fr;
#pragma unroll
  for (int n = 0; n < 4; ++n) {
    int col = cbase + n * 16;
    float bn = bias[col];
#pragma unroll
    for (int m = 0; m < 4; ++m) {
      int row = rbase + m * 16;
#pragma unroll
      for (int q = 0; q < 4; ++q)
        C[(size_t)(row + q) * NQKV + col] = f2bf(acc[m][n][q] + bn);
    }
  }
}

// ========== O GEMM: 64x128 tile (512 blocks = 2/CU), BK=32, 2-phase dbuf ==========
__global__ __launch_bounds__(256) void gemm_o(
    const u16* __restrict__ A, const u16* __restrict__ B,
    const float* __restrict__ bias, float* __restrict__ C) {
  __shared__ u16 sA[2][64 * 32], sB[2][128 * 32];
  int t = threadIdx.x, w = t >> 6, lane = t & 63;
  int bid = blockIdx.y * 4 + blockIdx.x;
  int swz = (bid & 7) * 64 + (bid >> 3);
  long m0 = (long)(swz / 4) * 64, n0 = (long)(swz % 4) * 128;
  int wn = w * 32;
  int fr = lane & 15, fo = lane >> 4;
  int rl = lane >> 2, cb = (lane & 3) * 16;
  const char* Ab = (const char*)A;
  const char* Bb = (const char*)B;

  f32x4 acc[4][2] = {};

#define STAGE_O(buf, kt)                                                    \
  do {                                                                      \
    int ra = w * 16 + rl;                                                   \
    stage16(Ab + ((m0 + ra) * 512 + (long)(kt) * 32) * 2 + cb,              \
            (char*)sA[buf] + w * 1024);                                     \
    int c0 = w, c1 = w + 4;                                                 \
    int r0 = c0 * 16 + rl, r1 = c1 * 16 + rl;                               \
    stage16(Bb + ((n0 + r0) * 512 + (long)(kt) * 32) * 2 + cb,              \
            (char*)sB[buf] + c0 * 1024);                                    \
    stage16(Bb + ((n0 + r1) * 512 + (long)(kt) * 32) * 2 + cb,              \
            (char*)sB[buf] + c1 * 1024);                                    \
  } while (0)

  STAGE_O(0, 0);
  __syncthreads();

  for (int kt = 0; kt < 16; ++kt) {
    int cur = kt & 1;
    if (kt < 15) STAGE_O(cur ^ 1, kt + 1);
    bf16x8 af[4], bf[2];
#pragma unroll
    for (int m = 0; m < 4; ++m)
      af[m] = *(const bf16x8*)&sA[cur][(m * 16 + fr) * 32 + fo * 8];
#pragma unroll
    for (int n = 0; n < 2; ++n)
      bf[n] = *(const bf16x8*)&sB[cur][(wn + n * 16 + fr) * 32 + fo * 8];
#pragma unroll
    for (int m = 0; m < 4; ++m)
#pragma unroll
      for (int n = 0; n < 2; ++n)
        acc[m][n] = __builtin_amdgcn_mfma_f32_16x16x32_bf16(af[m], bf[n], acc[m][n], 0, 0, 0);
    __syncthreads();
  }
#undef STAGE_O

  int rbase = m0 + fo * 4, cbase = n0 + wn + fr;
#pragma unroll
  for (int n = 0; n < 2; ++n) {
    int col = cbase + n * 16;
    float bn = bias[col];
#pragma unroll
    for (int m = 0; m < 4; ++m) {
      int row = rbase + m * 16;
#pragma unroll
      for (int q = 0; q < 4; ++q)
        C[(size_t)(row + q) * 512 + col] = acc[m][n][q] + bn;
    }
  }
}

// ================= banded flash-attention on MFMA (defensive rewrite) =================
// Block = (b, h, 128-query tile), 4 waves, q-tiles qt = w*2 + qi.
// LDS (padded, reg-staged): sQ[128][72] u16 | sK[160][72] (rows l0-16..l0+143)
//   | sVT[64][176] (cols 160..175 zeroed) | sP[16][72] per wave (cols 48..63 zeroed).
// Frag reads at 144B/352B row strides: uniform 8 dword-accesses/bank (conflict-free).
#define ATTN_LDS 73216

__global__ __launch_bounds__(256) void attn_mfma(const u16* __restrict__ QKV,
                                                 u16* __restrict__ AOh) {
  extern __shared__ char lds[];
  u16* sQ = (u16*)lds;                     // [128][72]
  u16* sK = (u16*)(lds + 18432);           // [160][72]
  u16* sVT = (u16*)(lds + 41472);          // [64][176]
  int t = threadIdx.x, w = t >> 6, lane = t & 63;
  u16* sP = (u16*)(lds + 64000 + w * 2304);  // [16][72] wave-private

  int blk = blockIdx.x;
  int tile = blk & 15, h = (blk >> 4) & 7, b = blk >> 7;
  int l0 = tile * 128;
  const u16* base = QKV + (size_t)b * L_SEQ * NQKV + h * D_K;

  // ---- stage Q: 1024 (row, d-octet) tasks
#pragma unroll
  for (int i = 0; i < 4; ++i) {
    int task = t + i * 256;
    int row = task >> 3, oct = task & 7;
    u16x8 g = *(const u16x8*)(base + (size_t)(l0 + row) * NQKV + oct * 8);
    *(u16x8*)(sQ + row * 72 + oct * 8) = g;
  }
  // ---- stage K: 1280 tasks (rows clamped)
#pragma unroll
  for (int i = 0; i < 5; ++i) {
    int task = t + i * 256;
    int row = task >> 3, oct = task & 7;
    int l = min(max(l0 - 16 + row, 0), L_SEQ - 1);
    u16x8 g = *(const u16x8*)(base + (size_t)l * NQKV + 512 + oct * 8);
    *(u16x8*)(sK + row * 72 + oct * 8) = g;
  }
  // ---- stage V^T: 1280 tasks, scalar transpose
#pragma unroll
  for (int i = 0; i < 5; ++i) {
    int task = t + i * 256;
    int kv = task >> 3, oct = task & 7;
    int l = min(max(l0 - 16 + kv, 0), L_SEQ - 1);
    u16x8 g = *(const u16x8*)(base + (size_t)l * NQKV + 1024 + oct * 8);
#pragma unroll
    for (int e = 0; e < 8; ++e)
      sVT[(oct * 8 + e) * 176 + kv] = g[e];
  }
  // ---- zero sVT cols 160..175 (64 d-rows x 16)
  if (t < 128) {
    u16x8 z = {};
    *(u16x8*)(sVT + (t >> 1) * 176 + 160 + (t & 1) * 8) = z;
  }
  // ---- zero sP cols 48..63 (16 rows x 16), wave-private
  if (lane < 32) {
    u16x8 z = {};
    *(u16x8*)(sP + (lane >> 1) * 72 + 48 + (lane & 1) * 8) = z;
  }
  __syncthreads();

  int fr = lane & 15, fo = lane >> 4;

  for (int qi = 0; qi < 2; ++qi) {
    if (qi) __syncthreads();  // protect sP (rewritten) across passes
    int qt = w * 2 + qi;

    // Q A-frags: row = qt*16+fr, k = ks*32 + fo*8 + e
    bf16x8 Aq[2];
#pragma unroll
    for (int ks = 0; ks < 2; ++ks)
      Aq[ks] = *(const bf16x8*)(sQ + (qt * 16 + fr) * 72 + ks * 32 + fo * 8);

    // QK^T: 3 key tiles (sK rows qt*16 + kt*16 + fr)
    f32x4 sc[3] = {};
#pragma unroll
    for (int kt = 0; kt < 3; ++kt)
#pragma unroll
      for (int ks = 0; ks < 2; ++ks) {
        bf16x8 Bk = *(const bf16x8*)(sK + (qt * 16 + kt * 16 + fr) * 72 + ks * 32 + fo * 8);
        sc[kt] = __builtin_amdgcn_mfma_f32_16x16x32_bf16(Aq[ks], Bk, sc[kt], 0, 0, 0);
      }

    // masked softmax; C-frag: row(query) = fo*4+j, col(key) = fr
    float pj[3][4], mj[4], rj[4];
#pragma unroll
    for (int j = 0; j < 4; ++j) {
      int irow = l0 + qt * 16 + fo * 4 + j;
      float mloc = -1.0e30f;
#pragma unroll
      for (int kt = 0; kt < 3; ++kt) {
        int jcol = l0 - 16 + qt * 16 + kt * 16 + fr;
        float sv = fminf(fmaxf(sc[kt][j] * 0.125f, -10000.f), 10000.f);
        int dd = irow - jcol;
        bool ok = (dd <= WIN) && (dd >= -WIN) && (jcol >= 0) && (jcol < L_SEQ);
        sv = ok ? sv : -1.0e30f;
        pj[kt][j] = sv;
        mloc = fmaxf(mloc, sv);
      }
      mj[j] = mloc;
    }
#pragma unroll
    for (int st = 1; st <= 8; st <<= 1)
#pragma unroll
      for (int j = 0; j < 4; ++j)
        mj[j] = fmaxf(mj[j], __shfl_xor(mj[j], st));
#pragma unroll
    for (int j = 0; j < 4; ++j) {
      float r = 0.f;
#pragma unroll
      for (int kt = 0; kt < 3; ++kt) {
        float e = (pj[kt][j] > -1.0e29f) ? __expf(pj[kt][j] - mj[j]) : 0.f;
        pj[kt][j] = e;
        r += e;
      }
      rj[j] = r;
    }
#pragma unroll
    for (int st = 1; st <= 8; st <<= 1)
#pragma unroll
      for (int j = 0; j < 4; ++j)
        rj[j] += __shfl_xor(rj[j], st);
#pragma unroll
    for (int j = 0; j < 4; ++j) rj[j] = 1.f / rj[j];

    // P -> LDS as A-frag source: [16 q-rows][72], cols 0..47 real, 48..63 zero
#pragma unroll
    for (int kt = 0; kt < 3; ++kt)
#pragma unroll
      for (int j = 0; j < 4; ++j)
        sP[(fo * 4 + j) * 72 + kt * 16 + fr] = f2bf(pj[kt][j] * rj[j]);

    // PV: A = P (row=q, k=c), B = V^T (row=d, k-col = qt*16 + c)
    f32x4 oa[4] = {};
#pragma unroll
    for (int ks = 0; ks < 2; ++ks) {
      bf16x8 Ap = *(const bf16x8*)(sP + fr * 72 + ks * 32 + fo * 8);
#pragma unroll
      for (int nt = 0; nt < 4; ++nt) {
        bf16x8 Bv = *(const bf16x8*)(sVT + (nt * 16 + fr) * 176 + qt * 16 + ks * 32 + fo * 8);
        oa[nt] = __builtin_amdgcn_mfma_f32_16x16x32_bf16(Ap, Bv, oa[nt], 0, 0, 0);
      }
    }

    // store: row = query, col = h*64 + nt*16 + fr
#pragma unroll
    for (int nt = 0; nt < 4; ++nt)
#pragma unroll
      for (int j = 0; j < 4; ++j) {
        size_t row = (size_t)b * L_SEQ + l0 + qt * 16 + fo * 4 + j;
        AOh[row * D_MODEL + h * D_K + nt * 16 + fr] = f2bf(oa[nt][j]);
      }
  }
}

extern "C" void kernel_launch(void* const* d_in, const int* in_sizes, int n_in,
                              void* d_out, int out_size, void* d_ws, size_t ws_size,
                              hipStream_t stream) {
  const float* Q  = (const float*)d_in[0];
  const float* Wq = (const float*)d_in[1];
  const float* bq = (const float*)d_in[2];
  const float* Wk = (const float*)d_in[3];
  const float* bk = (const float*)d_in[4];
  const float* Wv = (const float*)d_in[5];
  const float* bv = (const float*)d_in[6];
  const float* Wo = (const float*)d_in[7];
  const float* bo = (const float*)d_in[8];
  float* out = (float*)d_out;

  char* p = (char*)d_ws;
  u16* Xh = (u16*)p;        p += (size_t)M_ROWS * 512 * 2;
  u16* Bqkv = (u16*)p;      p += (size_t)1536 * 512 * 2;
  u16* Bo = (u16*)p;        p += (size_t)512 * 512 * 2;
  float* bias_qkv = (float*)p; p += 1536 * 4;
  u16* QKV = (u16*)p;       p += (size_t)M_ROWS * 1536 * 2;
  u16* AOh = (u16*)p;       p += (size_t)M_ROWS * 512 * 2;

  hipFuncSetAttribute((const void*)attn_mfma,
                      hipFuncAttributeMaxDynamicSharedMemorySize, ATTN_LDS);

  hipLaunchKernelGGL(prep, dim3(4353), dim3(256), 0, stream,
                     Q, Wq, Wk, Wv, Wo, bq, bk, bv, Xh, Bqkv, Bo, bias_qkv);

  // QKV: 12 n-tiles x 64 m-tiles = 768 blocks (3/CU)
  gemm_qkv<<<dim3(12, 64), dim3(256), 0, stream>>>(Xh, Bqkv, bias_qkv, QKV);

  // attn: (b, h, tile) = 4*8*16 = 512 blocks (2/CU)
  hipLaunchKernelGGL(attn_mfma, dim3(512), dim3(256), ATTN_LDS, stream, QKV, AOh);

  // O: 4 n-tiles x 128 m-tiles = 512 blocks (2/CU)
  gemm_o<<<dim3(4, 128), dim3(256), 0, stream>>>(AOh, Bo, bo, out);
}